// Round 9
// baseline (384.560 us; speedup 1.0000x reference)
//
#include <hip/hip_runtime.h>
#include <hip/hip_bf16.h>
#include <math.h>

#define S_LEN 2048
#define BATCH 2
#define DMODEL 1024
#define NH 16
#define NKV 4
#define HDIM 64
#define EPS 1e-5f
#define MROWS (S_LEN*BATCH)  // 4096
#define QSCALE (0.03125f * 1.44269504088896f)

#define AS1 __attribute__((address_space(1)))
#define AS3 __attribute__((address_space(3)))

typedef __attribute__((ext_vector_type(8))) short bf8_t;
typedef __attribute__((ext_vector_type(4))) float f4_t;
typedef _Float16 __attribute__((ext_vector_type(8))) h8_t;
typedef _Float16 __attribute__((ext_vector_type(4))) h4_t;

#define MFMA16(a,b,c) __builtin_amdgcn_mfma_f32_16x16x16f16(a,b,c,0,0,0)

__device__ __forceinline__ float exp2_fast(float x){ return __builtin_exp2f(x); }

__device__ __forceinline__ unsigned short f2bf(float f){
  __hip_bfloat16 b = __float2bfloat16(f);
  return __builtin_bit_cast(unsigned short, b);
}
__device__ __forceinline__ float bf2f(unsigned short u){
  return __builtin_bit_cast(float, (unsigned)u << 16);
}
__device__ __forceinline__ float gelu_f(float x){
  return 0.5f * x * (1.0f + erff(x * 0.7071067811865475f));
}

// ------- prep: weight transposes (blocks 0..10751) + RMSNorm1 (rest) ---------
__global__ __launch_bounds__(256) void prep_k(const float* __restrict__ wq, const float* __restrict__ wk,
                                              const float* __restrict__ wv, const float* __restrict__ wo,
                                              const float* __restrict__ w1, const float* __restrict__ w2,
                                              __hip_bfloat16* __restrict__ wqkv_t, __hip_bfloat16* __restrict__ wo_t,
                                              __hip_bfloat16* __restrict__ w1_t,   __hip_bfloat16* __restrict__ w2_t,
                                              const float* __restrict__ x, const float* __restrict__ n1w,
                                              __hip_bfloat16* __restrict__ h){
  if (blockIdx.x < 10752){
    __shared__ float t[32][33];
    int b = blockIdx.x;
    const float* src; __hip_bfloat16* dst; int N, stride, nx;
    if (b < 1024)      { src=wq; dst=wqkv_t;               N=1024; stride=1024; nx=32;  }
    else if (b < 1280) { b-=1024; src=wk; dst=wqkv_t+1024*1024; N=256; stride=1024; nx=8; }
    else if (b < 1536) { b-=1280; src=wv; dst=wqkv_t+1280*1024; N=256; stride=1024; nx=8; }
    else if (b < 2560) { b-=1536; src=wo; dst=wo_t;        N=1024; stride=1024; nx=32;  }
    else if (b < 6656) { b-=2560; src=w1; dst=w1_t;        N=4096; stride=1024; nx=128; }
    else               { b-=6656; src=w2; dst=w2_t;        N=1024; stride=4096; nx=32;  }
    int n0 = (b % nx)*32, k0 = (b / nx)*32;
    int tx = threadIdx.x & 31, ty = threadIdx.x >> 5;
    #pragma unroll
    for (int i = 0; i < 4; ++i)
      t[ty*4+i][tx] = src[(size_t)(k0+ty*4+i)*N + n0 + tx];
    __syncthreads();
    #pragma unroll
    for (int i = 0; i < 4; ++i)
      dst[(size_t)(n0+ty*4+i)*stride + k0 + tx] = __float2bfloat16(t[tx][ty*4+i]);
  } else {
    __shared__ float sm[5];
    size_t row = blockIdx.x - 10752;
    const float4* xr = (const float4*)(x + row * DMODEL);
    float4 v = xr[threadIdx.x];
    float ss = v.x*v.x + v.y*v.y + v.z*v.z + v.w*v.w;
    #pragma unroll
    for (int off = 32; off; off >>= 1) ss += __shfl_down(ss, off);
    if ((threadIdx.x & 63) == 0) sm[threadIdx.x >> 6] = ss;
    __syncthreads();
    if (threadIdx.x == 0) sm[4] = rsqrtf((sm[0]+sm[1]+sm[2]+sm[3]) * (1.0f/DMODEL) + EPS);
    __syncthreads();
    float r = sm[4];
    float4 wv4 = ((const float4*)n1w)[threadIdx.x];
    ushort4 ob;
    ob.x = f2bf(v.x*r*wv4.x); ob.y = f2bf(v.y*r*wv4.y);
    ob.z = f2bf(v.z*r*wv4.z); ob.w = f2bf(v.w*r*wv4.w);
    ((ushort4*)(h + row * DMODEL))[threadIdx.x] = ob;
  }
}

// ---------------- bf16 MFMA GEMM, 128x128 ----------------------------------
// C[M,N] = A[M,K] @ Wt[N,K]^T. 128x128 tile, BK=64, 4 waves (2x2), 4x4 16x16.
// R9: SINGLE-BUFFER only (32KB LDS). R8's full-line staging lifted the
// per-instruction transaction wall (+38%); the remaining gap to m97's
// 52 B/cyc/CU staging is residency: dbuf's 64KB LDS caps at 2 blocks/CU,
// m97 runs 3 at 32KB. Single-buffer + full-line + 2D-XCD swizzle.
// Full-line staging: lane l -> row (l>>3), k-chunk ((l&7) ^ (l>>3)): 8 rows
// x 128B full lines per instruction, each line touched once. LDS linear
// [128][64]; read XOR (s*32+lc*8)^(lr&7)*8 (verified 0 conflicts, R8).
// EPI: 1 = +bias,gelu->bf16 ; 3 = raw bf16 partial -> Cb + z*MROWS*N
template<int EPI>
__global__ __launch_bounds__(256) void mgemm_k(const __hip_bfloat16* __restrict__ A,
                                               const __hip_bfloat16* __restrict__ Wt,
                                               const float* __restrict__ bias,
                                               __hip_bfloat16* __restrict__ Cb,
                                               int N, int Kstride, int kLen, int sy){
  __shared__ __align__(16) __hip_bfloat16 As[8192];   // [128][64] row-major
  __shared__ __align__(16) __hip_bfloat16 Bs[8192];
  const int tid = threadIdx.x;
  const int w = tid >> 6, l = tid & 63;
  const int lr = l & 15, lc = l >> 4;        // fragment-read coords
  const int lr7 = lr & 7;
  const int rrow = l >> 3;                   // staging: row within 8-group
  const int kch  = (l & 7) ^ rrow;           // staging: XOR-permuted k-chunk

  // ---- 2-D XCD-locality block mapping (R7) ----
  const unsigned gx = gridDim.x, gy = gridDim.y;
  unsigned hb  = (blockIdx.z * gy + blockIdx.y) * gx + blockIdx.x;
  unsigned xcd = hb & 7u;
  unsigned i   = hb >> 3;
  unsigned cgPerX = (gx * gridDim.z) >> 3;
  unsigned stSz = cgPerX * (unsigned)sy;
  unsigned st  = i / stSz, rr2 = i % stSz;
  unsigned cgl = rr2 % cgPerX, yy = rr2 / cgPerX;
  unsigned byi = st * (unsigned)sy + yy;
  unsigned cg  = xcd * cgPerX + cgl;
  unsigned bxi = cg % gx;
  unsigned bzi = cg / gx;

  const int bm = byi * 128, bn = bxi * 128;
  const int wm = (w >> 1) * 64, wn = (w & 1) * 64;
  const int kOff = bzi * kLen;

  // staging base pointers: wave w stages rows 32w..32w+31 of both tiles
  const __hip_bfloat16* Ag = A  + (size_t)(bm + 32*w + rrow)*Kstride + kOff + kch*8;
  const __hip_bfloat16* Bg = Wt + (size_t)(bn + 32*w + rrow)*Kstride + kOff + kch*8;

  f4_t acc[4][4] = {};

  auto stage = [&](int k0){
    #pragma unroll
    for (int ii = 0; ii < 4; ++ii){
      __builtin_amdgcn_global_load_lds((const AS1 void*)(Ag + (size_t)(8*ii)*Kstride + k0),
                                       (AS3 void*)(&As[w*2048 + ii*512 + l*8]), 16, 0, 0);
      __builtin_amdgcn_global_load_lds((const AS1 void*)(Bg + (size_t)(8*ii)*Kstride + k0),
                                       (AS3 void*)(&Bs[w*2048 + ii*512 + l*8]), 16, 0, 0);
    }
  };

  auto compute = [&](){
    #pragma unroll
    for (int s = 0; s < 2; ++s){
      const int kx = (s*32 + lc*8) ^ (lr7*8);
      bf8_t af[4], bfr[4];
      #pragma unroll
      for (int mi = 0; mi < 4; ++mi)
        af[mi] = *(const bf8_t*)(&As[(wm + mi*16 + lr)*64 + kx]);
      #pragma unroll
      for (int ni = 0; ni < 4; ++ni)
        bfr[ni] = *(const bf8_t*)(&Bs[(wn + ni*16 + lr)*64 + kx]);
      #pragma unroll
      for (int mi = 0; mi < 4; ++mi)
        #pragma unroll
        for (int ni = 0; ni < 4; ++ni)
          acc[mi][ni] = __builtin_amdgcn_mfma_f32_16x16x32_bf16(af[mi], bfr[ni], acc[mi][ni], 0, 0, 0);
    }
  };

  for (int k0 = 0; k0 < kLen; k0 += 64){
    __syncthreads();
    stage(k0);
    __syncthreads();   // compiler emits vmcnt(0) drain before barrier
    compute();
  }

  __hip_bfloat16* Cp = (EPI == 3) ? (Cb + (size_t)bzi * ((size_t)MROWS * N)) : Cb;

  // C/D layout: col = lane&15 (=lr), row = (lane>>4)*4 + r (=lc*4+r)
  #pragma unroll
  for (int ni = 0; ni < 4; ++ni){
    int col = bn + wn + ni*16 + lr;
    float bb = (EPI == 3) ? 0.0f : bias[col];
    #pragma unroll
    for (int mi = 0; mi < 4; ++mi){
      #pragma unroll
      for (int r = 0; r < 4; ++r){
        int row = bm + wm + mi*16 + lc*4 + r;
        size_t off = (size_t)row * N + col;
        float v = acc[mi][ni][r] + bb;
        if (EPI == 1) Cp[off] = __float2bfloat16(gelu_f(v));
        else          Cp[off] = __float2bfloat16(v);
      }
    }
  }
}

// -------- split-K reduce: out = sum_bf16(partials) + bias + res (fp32) -------
template<int NS>
__global__ __launch_bounds__(256) void reduce_k(const unsigned short* __restrict__ P,
                                                const float* __restrict__ bias,
                                                const float* __restrict__ res,
                                                float* __restrict__ out, int N){
  size_t i = ((size_t)blockIdx.x*256 + threadIdx.x) * 4;
  int col = (int)(i % (size_t)N);
  size_t stride = (size_t)MROWS * N;
  float a0=0,a1=0,a2=0,a3=0;
  #pragma unroll
  for (int p = 0; p < NS; ++p){
    ushort4 u = *(const ushort4*)(P + p*stride + i);
    a0 += bf2f(u.x); a1 += bf2f(u.y); a2 += bf2f(u.z); a3 += bf2f(u.w);
  }
  float4 bb = *(const float4*)(bias + col);
  float4 r4 = *(const float4*)(res + i);
  float4 o = make_float4(a0+bb.x+r4.x, a1+bb.y+r4.y, a2+bb.z+r4.z, a3+bb.w+r4.w);
  *(float4*)(out + i) = o;
}

// ---- fused: wo split-K reduce (+bias+res) -> x1, then RMSNorm2 -> h_bf ------
template<int NS>
__global__ __launch_bounds__(256) void redn_k(const unsigned short* __restrict__ P,
                                              const float* __restrict__ bias,
                                              const float* __restrict__ res,
                                              const float* __restrict__ nw,
                                              float* __restrict__ x1,
                                              __hip_bfloat16* __restrict__ h){
  __shared__ float sm[5];
  size_t row = blockIdx.x;
  size_t i = row * DMODEL + threadIdx.x*4;
  size_t stride = (size_t)MROWS * DMODEL;
  float4 bb = *(const float4*)(bias + threadIdx.x*4);
  float4 r4 = *(const float4*)(res + i);
  float4 v = make_float4(bb.x+r4.x, bb.y+r4.y, bb.z+r4.z, bb.w+r4.w);
  #pragma unroll
  for (int p = 0; p < NS; ++p){
    ushort4 u = *(const ushort4*)(P + p*stride + i);
    v.x += bf2f(u.x); v.y += bf2f(u.y); v.z += bf2f(u.z); v.w += bf2f(u.w);
  }
  *(float4*)(x1 + i) = v;
  float ss = v.x*v.x + v.y*v.y + v.z*v.z + v.w*v.w;
  #pragma unroll
  for (int off = 32; off; off >>= 1) ss += __shfl_down(ss, off);
  if ((threadIdx.x & 63) == 0) sm[threadIdx.x >> 6] = ss;
  __syncthreads();
  if (threadIdx.x == 0) sm[4] = rsqrtf((sm[0]+sm[1]+sm[2]+sm[3]) * (1.0f/DMODEL) + EPS);
  __syncthreads();
  float r = sm[4];
  float4 wv = ((const float4*)nw)[threadIdx.x];
  ushort4 ob;
  ob.x = f2bf(v.x*r*wv.x); ob.y = f2bf(v.y*r*wv.y);
  ob.z = f2bf(v.z*r*wv.z); ob.w = f2bf(v.w*r*wv.w);
  ((ushort4*)(h + row * DMODEL))[threadIdx.x] = ob;
}

// -------- per-head RMSNorm + RoPE -> f16, reads qkv partial pair + bias ------
__global__ __launch_bounds__(64) void rope2_k(const unsigned short* __restrict__ P,
                                              const float* __restrict__ bq, const float* __restrict__ bk,
                                              const float* __restrict__ qw, const float* __restrict__ kw,
                                              _Float16* __restrict__ qo, _Float16* __restrict__ ko){
  const int s = blockIdx.x;
  const int y = blockIdx.y;                  // b*20 + r ; r<16 -> Q head r, else K head r-16
  const int b = y / 20, r0 = y % 20;
  const bool isQ = (r0 < 16);
  const int hh = isQ ? r0 : (r0 - 16);
  const int col0 = isQ ? hh*64 : 1024 + hh*64;
  const int lane = threadIdx.x;
  const size_t pstride = (size_t)MROWS * 1536;
  size_t off = ((size_t)s * BATCH + b) * 1536 + col0 + lane;
  float v = bf2f(P[off]) + bf2f(P[off + pstride])
          + (isQ ? bq[hh*64 + lane] : bk[hh*64 + lane]);
  float ss = v * v;
  #pragma unroll
  for (int m = 32; m; m >>= 1) ss += __shfl_xor(ss, m);
  float rr = rsqrtf(ss * (1.0f/64.0f) + EPS);
  v = v * rr * (isQ ? qw[lane] : kw[lane]);
  int i = lane & 31;
  float invf = powf(10000.0f, -((float)(2*i)) * (1.0f/64.0f));
  float ang = (float)s * invf;
  float c, sn;
  sincosf(ang, &sn, &c);
  float partner = __shfl_xor(v, 32);
  float rh = (lane < 32) ? -partner : partner;
  float o = (v * c + rh * sn) * (isQ ? QSCALE : 1.0f);
  _Float16* outp = isQ ? (qo + (((size_t)b * NH  + hh) * S_LEN + s) * 64 + lane)
                       : (ko + (((size_t)b * NKV + hh) * S_LEN + s) * 64 + lane);
  *outp = (_Float16)o;
}

// -------- V extract from qkv partials -> Vt f16 [B*NKV][64][S] ---------------
__global__ __launch_bounds__(256) void vcast_k(const unsigned short* __restrict__ P,
                                               const float* __restrict__ bv,
                                               _Float16* __restrict__ Vt){
  __shared__ float t[64][65];
  const int s0 = blockIdx.x * 64;
  const int bkv = blockIdx.y;
  const int b = bkv >> 2, kv = bkv & 3;
  const int tid = threadIdx.x;
  const size_t pstride = (size_t)MROWS * 1536;
  #pragma unroll
  for (int i = 0; i < 16; ++i){
    int idx = tid + 256*i;
    int sl = idx >> 6, d = idx & 63;
    size_t off = ((size_t)(s0+sl)*BATCH + b)*1536 + 1280 + kv*64 + d;
    t[d][sl] = bf2f(P[off]) + bf2f(P[off + pstride]) + bv[kv*64 + d];
  }
  __syncthreads();
  #pragma unroll
  for (int i = 0; i < 16; ++i){
    int idx = tid + 256*i;
    int d = idx >> 6, sl = idx & 63;
    Vt[((size_t)bkv*64 + d)*S_LEN + s0 + sl] = (_Float16)t[d][sl];
  }
}

// ---------------- MFMA flash attention -------------------------------------
// R9: defer-max (T13). Skip the Od-rescale / m-update when the tile's
// per-row max grows by <= 8 (log2 domain; P bounded by 2^8=256, safe in
// f16 and f32 accum). HK uses THR=8; +5% measured on random data (m214).
__global__ __launch_bounds__(256) void attn2_k(const _Float16* __restrict__ Q,
                                               const _Float16* __restrict__ K,
                                               const _Float16* __restrict__ Vt,
                                               __hip_bfloat16* __restrict__ AO){
  __shared__ __align__(16) _Float16 Ks[8*512];
  __shared__ __align__(16) _Float16 Vs[8*512];
  const int bh = blockIdx.x;
  const int qb = (gridDim.y - 1) - blockIdx.y;
  const int b = bh >> 4, h = bh & 15;
  const int kvh = h >> 2;
  const int tid = threadIdx.x;
  const int w = tid >> 6, l = tid & 63;
  const int lr = l & 15, quad = l >> 4;

  const _Float16* qp = Q + ((size_t)bh * S_LEN + qb*64 + w*16 + lr) * 64;
  h8_t qf0 = *(const h8_t*)(qp + quad*8);
  h8_t qf1 = *(const h8_t*)(qp + 32 + quad*8);

  const _Float16* kbase = K  + (size_t)(b*NKV + kvh) * S_LEN * 64;
  const _Float16* vbase = Vt + (size_t)(b*NKV + kvh) * 64 * S_LEN;

  f4_t Od[4] = {};
  float m_i = -3.0e38f, l_i = 0.0f;

  for (int kt = 0; kt <= qb; ++kt){
    __syncthreads();
    #pragma unroll
    for (int ii = 0; ii < 4; ++ii){
      int i = w*4 + ii;
      if (i < 8){
        int cc = i >> 1, dh = i & 1;
        const _Float16* src = kbase + (size_t)(kt*64 + cc*16 + lr)*64 + dh*32 + quad*8;
        __builtin_amdgcn_global_load_lds((const AS1 void*)src, (AS3 void*)(Ks + i*512), 16, 0, 0);
      } else {
        int j = i - 8;
        int dd = j >> 1, cc32 = j & 1;
        const _Float16* src = vbase + (size_t)(dd*16 + lr)*S_LEN + kt*64 + cc32*32 + quad*8;
        __builtin_amdgcn_global_load_lds((const AS1 void*)src, (AS3 void*)(Vs + j*512), 16, 0, 0);
      }
    }
    __syncthreads();

    const bool diag = (kt == qb);
    f4_t sc[4];
    #pragma unroll
    for (int nc2 = 0; nc2 < 4; ++nc2){
      if (diag && nc2 > w){
        sc[nc2][0] = -1.0e30f; sc[nc2][1] = -1.0e30f;
        sc[nc2][2] = -1.0e30f; sc[nc2][3] = -1.0e30f;
        continue;
      }
      f4_t a = {};
      h8_t k0 = *(const h8_t*)(Ks + (nc2*2+0)*512 + l*8);
      h8_t k1 = *(const h8_t*)(Ks + (nc2*2+1)*512 + l*8);
      a = __builtin_amdgcn_mfma_f32_16x16x32_f16(k0, qf0, a, 0, 0, 0);
      a = __builtin_amdgcn_mfma_f32_16x16x32_f16(k1, qf1, a, 0, 0, 0);
      if (diag && nc2 == w){
        #pragma unroll
        for (int r = 0; r < 4; ++r)
          if (quad*4 + r > lr) a[r] = -1.0e30f;
      }
      sc[nc2] = a;
    }

    float mx = sc[0][0];
    #pragma unroll
    for (int nc2 = 0; nc2 < 4; ++nc2)
      #pragma unroll
      for (int r = 0; r < 4; ++r) mx = fmaxf(mx, sc[nc2][r]);
    mx = fmaxf(mx, __shfl_xor(mx, 16));
    mx = fmaxf(mx, __shfl_xor(mx, 32));
    // defer-max: only rescale when some row's max grew past m_i + 8
    if (!__all(mx <= m_i + 8.0f)){
      float nm = fmaxf(mx, m_i);
      float alpha = exp2_fast(m_i - nm);
      m_i = nm;
      l_i *= alpha;
      #pragma unroll
      for (int dd = 0; dd < 4; ++dd)
        #pragma unroll
        for (int r = 0; r < 4; ++r) Od[dd][r] *= alpha;
    }
    float rs = 0.0f;
    h4_t pf[4];
    #pragma unroll
    for (int nc2 = 0; nc2 < 4; ++nc2)
      #pragma unroll
      for (int r = 0; r < 4; ++r){
        float e = exp2_fast(sc[nc2][r] - m_i);
        rs += e;
        pf[nc2][r] = (_Float16)e;
      }
    rs += __shfl_xor(rs, 16);
    rs += __shfl_xor(rs, 32);
    l_i += rs;

    #pragma unroll
    for (int dd = 0; dd < 4; ++dd)
      #pragma unroll
      for (int nc2 = 0; nc2 < 4; ++nc2){
        if (diag && nc2 > w) continue;
        h4_t vf = *(const h4_t*)(Vs + (dd*2 + (nc2>>1))*512
                                 + (((nc2&1)*2 + (quad>>1))*16 + lr)*8 + (quad&1)*4);
        Od[dd] = MFMA16(vf, pf[nc2], Od[dd]);
      }
  }

  float inv = 1.0f / l_i;
  #pragma unroll
  for (int dd = 0; dd < 4; ++dd){
    ushort4 w4;
    w4.x = f2bf(Od[dd][0]*inv); w4.y = f2bf(Od[dd][1]*inv);
    w4.z = f2bf(Od[dd][2]*inv); w4.w = f2bf(Od[dd][3]*inv);
    size_t sg = (size_t)qb*64 + w*16 + lr;
    *(ushort4*)(AO + (sg*BATCH + b)*DMODEL + h*64 + dd*16 + quad*4) = w4;
  }
}

extern "C" void kernel_launch(void* const* d_in, const int* in_sizes, int n_in,
                              void* d_out, int out_size, void* d_ws, size_t ws_size,
                              hipStream_t stream){
  const float* x   = (const float*)d_in[0];
  const float* n1w = (const float*)d_in[1];
  const float* wq  = (const float*)d_in[2];
  const float* bq  = (const float*)d_in[3];
  const float* wk  = (const float*)d_in[4];
  const float* bk  = (const float*)d_in[5];
  const float* wv  = (const float*)d_in[6];
  const float* bv  = (const float*)d_in[7];
  const float* qnw = (const float*)d_in[8];
  const float* knw = (const float*)d_in[9];
  const float* wo  = (const float*)d_in[10];
  const float* bo  = (const float*)d_in[11];
  const float* n2w = (const float*)d_in[12];
  const float* w1  = (const float*)d_in[13];
  const float* b1  = (const float*)d_in[14];
  const float* w2  = (const float*)d_in[15];
  const float* b2  = (const float*)d_in[16];
  float* out = (float*)d_out;

  char* p = (char*)d_ws;
  auto carve = [&](size_t bytes)->char*{ char* r = p; p += (bytes + 255) & ~(size_t)255; return r; };
  __hip_bfloat16* h_bf   = (__hip_bfloat16*)carve((size_t)MROWS*DMODEL*2);
  __hip_bfloat16* ao_bf  = (__hip_bfloat16*)carve((size_t)MROWS*DMODEL*2);
  __hip_bfloat16* mid_bf = (__hip_bfloat16*)carve((size_t)MROWS*4096*2);
  __hip_bfloat16* wqkv_t = (__hip_bfloat16*)carve((size_t)1536*1024*2);
  __hip_bfloat16* wo_t   = (__hip_bfloat16*)carve((size_t)1024*1024*2);
  __hip_bfloat16* w1_t   = (__hip_bfloat16*)carve((size_t)4096*1024*2);
  __hip_bfloat16* w2_t   = (__hip_bfloat16*)carve((size_t)1024*4096*2);
  // shared scratch: qkv split-2 partials (25.2 MB) early, then wo/w2 split-2
  // partials (16.8 MB). Lifetimes disjoint (qkv_p dead after rope2/vcast).
  char* scratch = carve((size_t)2*MROWS*1536*2);
  __hip_bfloat16* qkv_p = (__hip_bfloat16*)scratch;   // 2*MROWS*1536*2
  __hip_bfloat16* ps    = (__hip_bfloat16*)scratch;   // 2*MROWS*1024*2 fits
  _Float16* q_f  = (_Float16*)carve((size_t)BATCH*NH *S_LEN*64*2);
  _Float16* k_f  = (_Float16*)carve((size_t)BATCH*NKV*S_LEN*64*2);
  _Float16* vt_f = (_Float16*)carve((size_t)BATCH*NKV*64*S_LEN*2);
  float* x1   = (float*)carve((size_t)MROWS*DMODEL*4);

  // weight prep + rmsnorm1 in one launch
  prep_k<<<10752 + MROWS, 256, 0, stream>>>(wq, wk, wv, wo, w1, w2,
                                            wqkv_t, wo_t, w1_t, w2_t, x, n1w, h_bf);

  // QKV: M=4096 N=1536 K=1024, split-K=2 (768 blocks), single-buf + 2D swizzle
  mgemm_k<3><<<dim3(12, 32, 2), 256, 0, stream>>>(h_bf, wqkv_t, nullptr, qkv_p, 1536, 1024, 512, 8);

  rope2_k<<<dim3(S_LEN, BATCH*20), 64, 0, stream>>>((const unsigned short*)qkv_p, bq, bk, qnw, knw, q_f, k_f);
  vcast_k<<<dim3(S_LEN/64, BATCH*NKV), 256, 0, stream>>>((const unsigned short*)qkv_p, bv, vt_f);
  attn2_k<<<dim3(BATCH*NH, S_LEN/64), 256, 0, stream>>>(q_f, k_f, vt_f, ao_bf);

  // O-proj: M=4096 N=1024 K=1024, split-K=2 (512 blocks), single-buf + 2D swizzle
  mgemm_k<3><<<dim3(8, 32, 2), 256, 0, stream>>>(ao_bf, wo_t, nullptr, ps, 1024, 1024, 512, 8);
  // fused: reduce(+bias+res) -> x1 AND rmsnorm2 -> h_bf
  redn_k<2><<<MROWS, 256, 0, stream>>>((const unsigned short*)ps, bo, x, n2w, x1, h_bf);

  // MLP up: M=4096 N=4096 K=1024 (1024 blocks), single-buf + 2D swizzle, gelu fused
  mgemm_k<1><<<dim3(32, 32, 1), 256, 0, stream>>>(h_bf, w1_t, b1, mid_bf, 4096, 1024, 1024, 8);

  // MLP down: M=4096 N=1024 K=4096, split-K=2 (512 blocks), single-buf + 2D swizzle
  mgemm_k<3><<<dim3(8, 32, 2), 256, 0, stream>>>(mid_bf, w2_t, nullptr, ps, 1024, 4096, 2048, 4);
  reduce_k<2><<<4096, 256, 0, stream>>>((const unsigned short*)ps, b2, x1, out, 1024);
}

// Round 10
// 372.633 us; speedup vs baseline: 1.0320x; 1.0320x over previous
//
#include <hip/hip_runtime.h>
#include <hip/hip_bf16.h>
#include <math.h>

#define S_LEN 2048
#define BATCH 2
#define DMODEL 1024
#define NH 16
#define NKV 4
#define HDIM 64
#define EPS 1e-5f
#define MROWS (S_LEN*BATCH)  // 4096
#define QSCALE (0.03125f * 1.44269504088896f)

#define AS1 __attribute__((address_space(1)))
#define AS3 __attribute__((address_space(3)))

typedef __attribute__((ext_vector_type(8))) short bf8_t;
typedef __attribute__((ext_vector_type(4))) float f4_t;
typedef _Float16 __attribute__((ext_vector_type(8))) h8_t;
typedef _Float16 __attribute__((ext_vector_type(4))) h4_t;

#define MFMA16(a,b,c) __builtin_amdgcn_mfma_f32_16x16x16f16(a,b,c,0,0,0)

__device__ __forceinline__ float exp2_fast(float x){ return __builtin_exp2f(x); }

__device__ __forceinline__ unsigned short f2bf(float f){
  __hip_bfloat16 b = __float2bfloat16(f);
  return __builtin_bit_cast(unsigned short, b);
}
__device__ __forceinline__ float bf2f(unsigned short u){
  return __builtin_bit_cast(float, (unsigned)u << 16);
}
__device__ __forceinline__ float gelu_f(float x){
  return 0.5f * x * (1.0f + erff(x * 0.7071067811865475f));
}

// ------- prep: weight transposes (blocks 0..10751) + RMSNorm1 (rest) ---------
__global__ __launch_bounds__(256) void prep_k(const float* __restrict__ wq, const float* __restrict__ wk,
                                              const float* __restrict__ wv, const float* __restrict__ wo,
                                              const float* __restrict__ w1, const float* __restrict__ w2,
                                              __hip_bfloat16* __restrict__ wqkv_t, __hip_bfloat16* __restrict__ wo_t,
                                              __hip_bfloat16* __restrict__ w1_t,   __hip_bfloat16* __restrict__ w2_t,
                                              const float* __restrict__ x, const float* __restrict__ n1w,
                                              __hip_bfloat16* __restrict__ h){
  if (blockIdx.x < 10752){
    __shared__ float t[32][33];
    int b = blockIdx.x;
    const float* src; __hip_bfloat16* dst; int N, stride, nx;
    if (b < 1024)      { src=wq; dst=wqkv_t;               N=1024; stride=1024; nx=32;  }
    else if (b < 1280) { b-=1024; src=wk; dst=wqkv_t+1024*1024; N=256; stride=1024; nx=8; }
    else if (b < 1536) { b-=1280; src=wv; dst=wqkv_t+1280*1024; N=256; stride=1024; nx=8; }
    else if (b < 2560) { b-=1536; src=wo; dst=wo_t;        N=1024; stride=1024; nx=32;  }
    else if (b < 6656) { b-=2560; src=w1; dst=w1_t;        N=4096; stride=1024; nx=128; }
    else               { b-=6656; src=w2; dst=w2_t;        N=1024; stride=4096; nx=32;  }
    int n0 = (b % nx)*32, k0 = (b / nx)*32;
    int tx = threadIdx.x & 31, ty = threadIdx.x >> 5;
    #pragma unroll
    for (int i = 0; i < 4; ++i)
      t[ty*4+i][tx] = src[(size_t)(k0+ty*4+i)*N + n0 + tx];
    __syncthreads();
    #pragma unroll
    for (int i = 0; i < 4; ++i)
      dst[(size_t)(n0+ty*4+i)*stride + k0 + tx] = __float2bfloat16(t[tx][ty*4+i]);
  } else {
    __shared__ float sm[5];
    size_t row = blockIdx.x - 10752;
    const float4* xr = (const float4*)(x + row * DMODEL);
    float4 v = xr[threadIdx.x];
    float ss = v.x*v.x + v.y*v.y + v.z*v.z + v.w*v.w;
    #pragma unroll
    for (int off = 32; off; off >>= 1) ss += __shfl_down(ss, off);
    if ((threadIdx.x & 63) == 0) sm[threadIdx.x >> 6] = ss;
    __syncthreads();
    if (threadIdx.x == 0) sm[4] = rsqrtf((sm[0]+sm[1]+sm[2]+sm[3]) * (1.0f/DMODEL) + EPS);
    __syncthreads();
    float r = sm[4];
    float4 wv4 = ((const float4*)n1w)[threadIdx.x];
    ushort4 ob;
    ob.x = f2bf(v.x*r*wv4.x); ob.y = f2bf(v.y*r*wv4.y);
    ob.z = f2bf(v.z*r*wv4.z); ob.w = f2bf(v.w*r*wv4.w);
    ((ushort4*)(h + row * DMODEL))[threadIdx.x] = ob;
  }
}

// ---------------- bf16 MFMA GEMM, 128x128 ----------------------------------
// C[M,N] = A[M,K] @ Wt[N,K]^T. 128x128 tile, BK=64, 4 waves (2x2), 4x4 16x16.
// R10 = R8 config (measured best): full-line staging + 2-D XCD swizzle;
// DB=true (2-phase dbuf) for K<=1024 GEMMs, DB=false for MLP-down.
// R9's all-single-buffer attempt regressed (MLP-up 65->77): occupancy did
// not rise and the per-iter drain was re-exposed. Dbuf at 2 blk/CU wins.
// Full-line staging: lane l -> row (l>>3), k-chunk ((l&7) ^ (l>>3)): 8 rows
// x 128B full lines per instruction, each line touched once. LDS linear
// [128][64]; read XOR (s*32+lc*8)^((lr&7)*8) (verified 0 conflicts, R8).
// EPI: 1 = +bias,gelu->bf16 ; 3 = raw bf16 partial -> Cb + z*MROWS*N
template<int EPI, bool DB>
__global__ __launch_bounds__(256) void mgemm_k(const __hip_bfloat16* __restrict__ A,
                                               const __hip_bfloat16* __restrict__ Wt,
                                               const float* __restrict__ bias,
                                               __hip_bfloat16* __restrict__ Cb,
                                               int N, int Kstride, int kLen, int sy){
  __shared__ __align__(16) __hip_bfloat16 As[DB?2:1][8192];   // [128][64] row-major
  __shared__ __align__(16) __hip_bfloat16 Bs[DB?2:1][8192];
  const int tid = threadIdx.x;
  const int w = tid >> 6, l = tid & 63;
  const int lr = l & 15, lc = l >> 4;        // fragment-read coords
  const int lr7 = lr & 7;
  const int rrow = l >> 3;                   // staging: row within 8-group
  const int kch  = (l & 7) ^ rrow;           // staging: XOR-permuted k-chunk

  // ---- 2-D XCD-locality block mapping (R7) ----
  const unsigned gx = gridDim.x, gy = gridDim.y;
  unsigned hb  = (blockIdx.z * gy + blockIdx.y) * gx + blockIdx.x;
  unsigned xcd = hb & 7u;
  unsigned i   = hb >> 3;
  unsigned cgPerX = (gx * gridDim.z) >> 3;
  unsigned stSz = cgPerX * (unsigned)sy;
  unsigned st  = i / stSz, rr2 = i % stSz;
  unsigned cgl = rr2 % cgPerX, yy = rr2 / cgPerX;
  unsigned byi = st * (unsigned)sy + yy;
  unsigned cg  = xcd * cgPerX + cgl;
  unsigned bxi = cg % gx;
  unsigned bzi = cg / gx;

  const int bm = byi * 128, bn = bxi * 128;
  const int wm = (w >> 1) * 64, wn = (w & 1) * 64;
  const int kOff = bzi * kLen;

  // staging base pointers: wave w stages rows 32w..32w+31 of both tiles
  const __hip_bfloat16* Ag = A  + (size_t)(bm + 32*w + rrow)*Kstride + kOff + kch*8;
  const __hip_bfloat16* Bg = Wt + (size_t)(bn + 32*w + rrow)*Kstride + kOff + kch*8;

  f4_t acc[4][4] = {};

  auto stage = [&](int buf, int k0){
    #pragma unroll
    for (int ii = 0; ii < 4; ++ii){
      __builtin_amdgcn_global_load_lds((const AS1 void*)(Ag + (size_t)(8*ii)*Kstride + k0),
                                       (AS3 void*)(&As[buf][w*2048 + ii*512 + l*8]), 16, 0, 0);
      __builtin_amdgcn_global_load_lds((const AS1 void*)(Bg + (size_t)(8*ii)*Kstride + k0),
                                       (AS3 void*)(&Bs[buf][w*2048 + ii*512 + l*8]), 16, 0, 0);
    }
  };

  auto compute = [&](int buf){
    #pragma unroll
    for (int s = 0; s < 2; ++s){
      const int kx = (s*32 + lc*8) ^ (lr7*8);
      bf8_t af[4], bfr[4];
      #pragma unroll
      for (int mi = 0; mi < 4; ++mi)
        af[mi] = *(const bf8_t*)(&As[buf][(wm + mi*16 + lr)*64 + kx]);
      #pragma unroll
      for (int ni = 0; ni < 4; ++ni)
        bfr[ni] = *(const bf8_t*)(&Bs[buf][(wn + ni*16 + lr)*64 + kx]);
      #pragma unroll
      for (int mi = 0; mi < 4; ++mi)
        #pragma unroll
        for (int ni = 0; ni < 4; ++ni)
          acc[mi][ni] = __builtin_amdgcn_mfma_f32_16x16x32_bf16(af[mi], bfr[ni], acc[mi][ni], 0, 0, 0);
    }
  };

  if constexpr (DB){
    const int nt = kLen >> 6;
    stage(0, 0);
    asm volatile("s_waitcnt vmcnt(0)" ::: "memory");
    __builtin_amdgcn_s_barrier();
    int cur = 0;
    for (int t = 0; t < nt; ++t){
      if (t + 1 < nt) stage(cur ^ 1, (t + 1) << 6);
      compute(cur);
      asm volatile("s_waitcnt vmcnt(0)" ::: "memory");
      __builtin_amdgcn_s_barrier();
      cur ^= 1;
    }
  } else {
    for (int k0 = 0; k0 < kLen; k0 += 64){
      __syncthreads();
      stage(0, k0);
      __syncthreads();
      compute(0);
    }
  }

  __hip_bfloat16* Cp = (EPI == 3) ? (Cb + (size_t)bzi * ((size_t)MROWS * N)) : Cb;

  // C/D layout: col = lane&15 (=lr), row = (lane>>4)*4 + r (=lc*4+r)
  #pragma unroll
  for (int ni = 0; ni < 4; ++ni){
    int col = bn + wn + ni*16 + lr;
    float bb = (EPI == 3) ? 0.0f : bias[col];
    #pragma unroll
    for (int mi = 0; mi < 4; ++mi){
      #pragma unroll
      for (int r = 0; r < 4; ++r){
        int row = bm + wm + mi*16 + lc*4 + r;
        size_t off = (size_t)row * N + col;
        float v = acc[mi][ni][r] + bb;
        if (EPI == 1) Cp[off] = __float2bfloat16(gelu_f(v));
        else          Cp[off] = __float2bfloat16(v);
      }
    }
  }
}

// -------- split-K reduce: out = sum_bf16(partials) + bias + res (fp32) -------
template<int NS>
__global__ __launch_bounds__(256) void reduce_k(const unsigned short* __restrict__ P,
                                                const float* __restrict__ bias,
                                                const float* __restrict__ res,
                                                float* __restrict__ out, int N){
  size_t i = ((size_t)blockIdx.x*256 + threadIdx.x) * 4;
  int col = (int)(i % (size_t)N);
  size_t stride = (size_t)MROWS * N;
  float a0=0,a1=0,a2=0,a3=0;
  #pragma unroll
  for (int p = 0; p < NS; ++p){
    ushort4 u = *(const ushort4*)(P + p*stride + i);
    a0 += bf2f(u.x); a1 += bf2f(u.y); a2 += bf2f(u.z); a3 += bf2f(u.w);
  }
  float4 bb = *(const float4*)(bias + col);
  float4 r4 = *(const float4*)(res + i);
  float4 o = make_float4(a0+bb.x+r4.x, a1+bb.y+r4.y, a2+bb.z+r4.z, a3+bb.w+r4.w);
  *(float4*)(out + i) = o;
}

// ---- fused: wo split-K reduce (+bias+res) -> x1, then RMSNorm2 -> h_bf ------
template<int NS>
__global__ __launch_bounds__(256) void redn_k(const unsigned short* __restrict__ P,
                                              const float* __restrict__ bias,
                                              const float* __restrict__ res,
                                              const float* __restrict__ nw,
                                              float* __restrict__ x1,
                                              __hip_bfloat16* __restrict__ h){
  __shared__ float sm[5];
  size_t row = blockIdx.x;
  size_t i = row * DMODEL + threadIdx.x*4;
  size_t stride = (size_t)MROWS * DMODEL;
  float4 bb = *(const float4*)(bias + threadIdx.x*4);
  float4 r4 = *(const float4*)(res + i);
  float4 v = make_float4(bb.x+r4.x, bb.y+r4.y, bb.z+r4.z, bb.w+r4.w);
  #pragma unroll
  for (int p = 0; p < NS; ++p){
    ushort4 u = *(const ushort4*)(P + p*stride + i);
    v.x += bf2f(u.x); v.y += bf2f(u.y); v.z += bf2f(u.z); v.w += bf2f(u.w);
  }
  *(float4*)(x1 + i) = v;
  float ss = v.x*v.x + v.y*v.y + v.z*v.z + v.w*v.w;
  #pragma unroll
  for (int off = 32; off; off >>= 1) ss += __shfl_down(ss, off);
  if ((threadIdx.x & 63) == 0) sm[threadIdx.x >> 6] = ss;
  __syncthreads();
  if (threadIdx.x == 0) sm[4] = rsqrtf((sm[0]+sm[1]+sm[2]+sm[3]) * (1.0f/DMODEL) + EPS);
  __syncthreads();
  float r = sm[4];
  float4 wv = ((const float4*)nw)[threadIdx.x];
  ushort4 ob;
  ob.x = f2bf(v.x*r*wv.x); ob.y = f2bf(v.y*r*wv.y);
  ob.z = f2bf(v.z*r*wv.z); ob.w = f2bf(v.w*r*wv.w);
  ((ushort4*)(h + row * DMODEL))[threadIdx.x] = ob;
}

// -------- per-head RMSNorm + RoPE -> f16, reads qkv partial pair + bias ------
__global__ __launch_bounds__(64) void rope2_k(const unsigned short* __restrict__ P,
                                              const float* __restrict__ bq, const float* __restrict__ bk,
                                              const float* __restrict__ qw, const float* __restrict__ kw,
                                              _Float16* __restrict__ qo, _Float16* __restrict__ ko){
  const int s = blockIdx.x;
  const int y = blockIdx.y;                  // b*20 + r ; r<16 -> Q head r, else K head r-16
  const int b = y / 20, r0 = y % 20;
  const bool isQ = (r0 < 16);
  const int hh = isQ ? r0 : (r0 - 16);
  const int col0 = isQ ? hh*64 : 1024 + hh*64;
  const int lane = threadIdx.x;
  const size_t pstride = (size_t)MROWS * 1536;
  size_t off = ((size_t)s * BATCH + b) * 1536 + col0 + lane;
  float v = bf2f(P[off]) + bf2f(P[off + pstride])
          + (isQ ? bq[hh*64 + lane] : bk[hh*64 + lane]);
  float ss = v * v;
  #pragma unroll
  for (int m = 32; m; m >>= 1) ss += __shfl_xor(ss, m);
  float rr = rsqrtf(ss * (1.0f/64.0f) + EPS);
  v = v * rr * (isQ ? qw[lane] : kw[lane]);
  int i = lane & 31;
  float invf = powf(10000.0f, -((float)(2*i)) * (1.0f/64.0f));
  float ang = (float)s * invf;
  float c, sn;
  sincosf(ang, &sn, &c);
  float partner = __shfl_xor(v, 32);
  float rh = (lane < 32) ? -partner : partner;
  float o = (v * c + rh * sn) * (isQ ? QSCALE : 1.0f);
  _Float16* outp = isQ ? (qo + (((size_t)b * NH  + hh) * S_LEN + s) * 64 + lane)
                       : (ko + (((size_t)b * NKV + hh) * S_LEN + s) * 64 + lane);
  *outp = (_Float16)o;
}

// -------- V extract from qkv partials -> Vt f16 [B*NKV][64][S] ---------------
__global__ __launch_bounds__(256) void vcast_k(const unsigned short* __restrict__ P,
                                               const float* __restrict__ bv,
                                               _Float16* __restrict__ Vt){
  __shared__ float t[64][65];
  const int s0 = blockIdx.x * 64;
  const int bkv = blockIdx.y;
  const int b = bkv >> 2, kv = bkv & 3;
  const int tid = threadIdx.x;
  const size_t pstride = (size_t)MROWS * 1536;
  #pragma unroll
  for (int i = 0; i < 16; ++i){
    int idx = tid + 256*i;
    int sl = idx >> 6, d = idx & 63;
    size_t off = ((size_t)(s0+sl)*BATCH + b)*1536 + 1280 + kv*64 + d;
    t[d][sl] = bf2f(P[off]) + bf2f(P[off + pstride]) + bv[kv*64 + d];
  }
  __syncthreads();
  #pragma unroll
  for (int i = 0; i < 16; ++i){
    int idx = tid + 256*i;
    int d = idx >> 6, sl = idx & 63;
    Vt[((size_t)bkv*64 + d)*S_LEN + s0 + sl] = (_Float16)t[d][sl];
  }
}

// ---------------- MFMA flash attention -------------------------------------
// defer-max (T13, kept from R9): skip the Od-rescale / m-update when the
// tile's per-row max grows by <= 8 (log2 domain; P bounded by 2^8=256,
// safe in f16 and f32 accum). HK uses THR=8.
__global__ __launch_bounds__(256) void attn2_k(const _Float16* __restrict__ Q,
                                               const _Float16* __restrict__ K,
                                               const _Float16* __restrict__ Vt,
                                               __hip_bfloat16* __restrict__ AO){
  __shared__ __align__(16) _Float16 Ks[8*512];
  __shared__ __align__(16) _Float16 Vs[8*512];
  const int bh = blockIdx.x;
  const int qb = (gridDim.y - 1) - blockIdx.y;
  const int b = bh >> 4, h = bh & 15;
  const int kvh = h >> 2;
  const int tid = threadIdx.x;
  const int w = tid >> 6, l = tid & 63;
  const int lr = l & 15, quad = l >> 4;

  const _Float16* qp = Q + ((size_t)bh * S_LEN + qb*64 + w*16 + lr) * 64;
  h8_t qf0 = *(const h8_t*)(qp + quad*8);
  h8_t qf1 = *(const h8_t*)(qp + 32 + quad*8);

  const _Float16* kbase = K  + (size_t)(b*NKV + kvh) * S_LEN * 64;
  const _Float16* vbase = Vt + (size_t)(b*NKV + kvh) * 64 * S_LEN;

  f4_t Od[4] = {};
  float m_i = -3.0e38f, l_i = 0.0f;

  for (int kt = 0; kt <= qb; ++kt){
    __syncthreads();
    #pragma unroll
    for (int ii = 0; ii < 4; ++ii){
      int i = w*4 + ii;
      if (i < 8){
        int cc = i >> 1, dh = i & 1;
        const _Float16* src = kbase + (size_t)(kt*64 + cc*16 + lr)*64 + dh*32 + quad*8;
        __builtin_amdgcn_global_load_lds((const AS1 void*)src, (AS3 void*)(Ks + i*512), 16, 0, 0);
      } else {
        int j = i - 8;
        int dd = j >> 1, cc32 = j & 1;
        const _Float16* src = vbase + (size_t)(dd*16 + lr)*S_LEN + kt*64 + cc32*32 + quad*8;
        __builtin_amdgcn_global_load_lds((const AS1 void*)src, (AS3 void*)(Vs + j*512), 16, 0, 0);
      }
    }
    __syncthreads();

    const bool diag = (kt == qb);
    f4_t sc[4];
    #pragma unroll
    for (int nc2 = 0; nc2 < 4; ++nc2){
      if (diag && nc2 > w){
        sc[nc2][0] = -1.0e30f; sc[nc2][1] = -1.0e30f;
        sc[nc2][2] = -1.0e30f; sc[nc2][3] = -1.0e30f;
        continue;
      }
      f4_t a = {};
      h8_t k0 = *(const h8_t*)(Ks + (nc2*2+0)*512 + l*8);
      h8_t k1 = *(const h8_t*)(Ks + (nc2*2+1)*512 + l*8);
      a = __builtin_amdgcn_mfma_f32_16x16x32_f16(k0, qf0, a, 0, 0, 0);
      a = __builtin_amdgcn_mfma_f32_16x16x32_f16(k1, qf1, a, 0, 0, 0);
      if (diag && nc2 == w){
        #pragma unroll
        for (int r = 0; r < 4; ++r)
          if (quad*4 + r > lr) a[r] = -1.0e30f;
      }
      sc[nc2] = a;
    }

    float mx = sc[0][0];
    #pragma unroll
    for (int nc2 = 0; nc2 < 4; ++nc2)
      #pragma unroll
      for (int r = 0; r < 4; ++r) mx = fmaxf(mx, sc[nc2][r]);
    mx = fmaxf(mx, __shfl_xor(mx, 16));
    mx = fmaxf(mx, __shfl_xor(mx, 32));
    // defer-max: only rescale when some row's max grew past m_i + 8
    if (!__all(mx <= m_i + 8.0f)){
      float nm = fmaxf(mx, m_i);
      float alpha = exp2_fast(m_i - nm);
      m_i = nm;
      l_i *= alpha;
      #pragma unroll
      for (int dd = 0; dd < 4; ++dd)
        #pragma unroll
        for (int r = 0; r < 4; ++r) Od[dd][r] *= alpha;
    }
    float rs = 0.0f;
    h4_t pf[4];
    #pragma unroll
    for (int nc2 = 0; nc2 < 4; ++nc2)
      #pragma unroll
      for (int r = 0; r < 4; ++r){
        float e = exp2_fast(sc[nc2][r] - m_i);
        rs += e;
        pf[nc2][r] = (_Float16)e;
      }
    rs += __shfl_xor(rs, 16);
    rs += __shfl_xor(rs, 32);
    l_i += rs;

    #pragma unroll
    for (int dd = 0; dd < 4; ++dd)
      #pragma unroll
      for (int nc2 = 0; nc2 < 4; ++nc2){
        if (diag && nc2 > w) continue;
        h4_t vf = *(const h4_t*)(Vs + (dd*2 + (nc2>>1))*512
                                 + (((nc2&1)*2 + (quad>>1))*16 + lr)*8 + (quad&1)*4);
        Od[dd] = MFMA16(vf, pf[nc2], Od[dd]);
      }
  }

  float inv = 1.0f / l_i;
  #pragma unroll
  for (int dd = 0; dd < 4; ++dd){
    ushort4 w4;
    w4.x = f2bf(Od[dd][0]*inv); w4.y = f2bf(Od[dd][1]*inv);
    w4.z = f2bf(Od[dd][2]*inv); w4.w = f2bf(Od[dd][3]*inv);
    size_t sg = (size_t)qb*64 + w*16 + lr;
    *(ushort4*)(AO + (sg*BATCH + b)*DMODEL + h*64 + dd*16 + quad*4) = w4;
  }
}

extern "C" void kernel_launch(void* const* d_in, const int* in_sizes, int n_in,
                              void* d_out, int out_size, void* d_ws, size_t ws_size,
                              hipStream_t stream){
  const float* x   = (const float*)d_in[0];
  const float* n1w = (const float*)d_in[1];
  const float* wq  = (const float*)d_in[2];
  const float* bq  = (const float*)d_in[3];
  const float* wk  = (const float*)d_in[4];
  const float* bk  = (const float*)d_in[5];
  const float* wv  = (const float*)d_in[6];
  const float* bv  = (const float*)d_in[7];
  const float* qnw = (const float*)d_in[8];
  const float* knw = (const float*)d_in[9];
  const float* wo  = (const float*)d_in[10];
  const float* bo  = (const float*)d_in[11];
  const float* n2w = (const float*)d_in[12];
  const float* w1  = (const float*)d_in[13];
  const float* b1  = (const float*)d_in[14];
  const float* w2  = (const float*)d_in[15];
  const float* b2  = (const float*)d_in[16];
  float* out = (float*)d_out;

  char* p = (char*)d_ws;
  auto carve = [&](size_t bytes)->char*{ char* r = p; p += (bytes + 255) & ~(size_t)255; return r; };
  __hip_bfloat16* h_bf   = (__hip_bfloat16*)carve((size_t)MROWS*DMODEL*2);
  __hip_bfloat16* ao_bf  = (__hip_bfloat16*)carve((size_t)MROWS*DMODEL*2);
  __hip_bfloat16* mid_bf = (__hip_bfloat16*)carve((size_t)MROWS*4096*2);
  __hip_bfloat16* wqkv_t = (__hip_bfloat16*)carve((size_t)1536*1024*2);
  __hip_bfloat16* wo_t   = (__hip_bfloat16*)carve((size_t)1024*1024*2);
  __hip_bfloat16* w1_t   = (__hip_bfloat16*)carve((size_t)4096*1024*2);
  __hip_bfloat16* w2_t   = (__hip_bfloat16*)carve((size_t)1024*4096*2);
  // shared scratch: qkv split-2 partials (25.2 MB) early, then wo/w2 split-2
  // partials (16.8 MB). Lifetimes disjoint (qkv_p dead after rope2/vcast).
  char* scratch = carve((size_t)2*MROWS*1536*2);
  __hip_bfloat16* qkv_p = (__hip_bfloat16*)scratch;   // 2*MROWS*1536*2
  __hip_bfloat16* ps    = (__hip_bfloat16*)scratch;   // 2*MROWS*1024*2 fits
  _Float16* q_f  = (_Float16*)carve((size_t)BATCH*NH *S_LEN*64*2);
  _Float16* k_f  = (_Float16*)carve((size_t)BATCH*NKV*S_LEN*64*2);
  _Float16* vt_f = (_Float16*)carve((size_t)BATCH*NKV*64*S_LEN*2);
  float* x1   = (float*)carve((size_t)MROWS*DMODEL*4);

  // weight prep + rmsnorm1 in one launch
  prep_k<<<10752 + MROWS, 256, 0, stream>>>(wq, wk, wv, wo, w1, w2,
                                            wqkv_t, wo_t, w1_t, w2_t, x, n1w, h_bf);

  // QKV: M=4096 N=1536 K=1024, split-K=2 (768 blocks), dbuf + 2D swizzle
  mgemm_k<3,true><<<dim3(12, 32, 2), 256, 0, stream>>>(h_bf, wqkv_t, nullptr, qkv_p, 1536, 1024, 512, 8);

  rope2_k<<<dim3(S_LEN, BATCH*20), 64, 0, stream>>>((const unsigned short*)qkv_p, bq, bk, qnw, knw, q_f, k_f);
  vcast_k<<<dim3(S_LEN/64, BATCH*NKV), 256, 0, stream>>>((const unsigned short*)qkv_p, bv, vt_f);
  attn2_k<<<dim3(BATCH*NH, S_LEN/64), 256, 0, stream>>>(q_f, k_f, vt_f, ao_bf);

  // O-proj: M=4096 N=1024 K=1024, split-K=2 (512 blocks), dbuf + 2D swizzle
  mgemm_k<3,true><<<dim3(8, 32, 2), 256, 0, stream>>>(ao_bf, wo_t, nullptr, ps, 1024, 1024, 512, 8);
  // fused: reduce(+bias+res) -> x1 AND rmsnorm2 -> h_bf
  redn_k<2><<<MROWS, 256, 0, stream>>>((const unsigned short*)ps, bo, x, n2w, x1, h_bf);

  // MLP up: M=4096 N=4096 K=1024 (1024 blocks), dbuf + 2D swizzle, gelu fused
  mgemm_k<1,true><<<dim3(32, 32, 1), 256, 0, stream>>>(h_bf, w1_t, b1, mid_bf, 4096, 1024, 1024, 8);

  // MLP down: M=4096 N=1024 K=4096, split-K=2 (512 blocks), single-buf + 2D swizzle
  mgemm_k<3,false><<<dim3(8, 32, 2), 256, 0, stream>>>(mid_bf, w2_t, nullptr, ps, 1024, 4096, 2048, 4);
  reduce_k<2><<<4096, 256, 0, stream>>>((const unsigned short*)ps, b2, x1, out, 1024);
}

// Round 11
// 353.474 us; speedup vs baseline: 1.0879x; 1.0542x over previous
//
#include <hip/hip_runtime.h>
#include <hip/hip_bf16.h>
#include <math.h>

#define S_LEN 2048
#define BATCH 2
#define DMODEL 1024
#define NH 16
#define NKV 4
#define HDIM 64
#define EPS 1e-5f
#define MROWS (S_LEN*BATCH)  // 4096
#define QSCALE (0.03125f * 1.44269504088896f)

#define AS1 __attribute__((address_space(1)))
#define AS3 __attribute__((address_space(3)))

typedef __attribute__((ext_vector_type(8))) short bf8_t;
typedef __attribute__((ext_vector_type(4))) float f4_t;
typedef _Float16 __attribute__((ext_vector_type(8))) h8_t;
typedef _Float16 __attribute__((ext_vector_type(4))) h4_t;

#define MFMA16(a,b,c) __builtin_amdgcn_mfma_f32_16x16x16f16(a,b,c,0,0,0)

__device__ __forceinline__ float exp2_fast(float x){ return __builtin_exp2f(x); }

__device__ __forceinline__ unsigned short f2bf(float f){
  __hip_bfloat16 b = __float2bfloat16(f);
  return __builtin_bit_cast(unsigned short, b);
}
__device__ __forceinline__ float bf2f(unsigned short u){
  return __builtin_bit_cast(float, (unsigned)u << 16);
}
__device__ __forceinline__ float gelu_f(float x){
  return 0.5f * x * (1.0f + erff(x * 0.7071067811865475f));
}

// -- prep: weight transposes (0..10751) + RMSNorm1 (..14847) + RoPE table ----
__global__ __launch_bounds__(256) void prep_k(const float* __restrict__ wq, const float* __restrict__ wk,
                                              const float* __restrict__ wv, const float* __restrict__ wo,
                                              const float* __restrict__ w1, const float* __restrict__ w2,
                                              __hip_bfloat16* __restrict__ wqkv_t, __hip_bfloat16* __restrict__ wo_t,
                                              __hip_bfloat16* __restrict__ w1_t,   __hip_bfloat16* __restrict__ w2_t,
                                              const float* __restrict__ x, const float* __restrict__ n1w,
                                              __hip_bfloat16* __restrict__ h,
                                              float* __restrict__ ctab, float* __restrict__ stab){
  if (blockIdx.x < 10752){
    __shared__ float t[32][33];
    int b = blockIdx.x;
    const float* src; __hip_bfloat16* dst; int N, stride, nx;
    if (b < 1024)      { src=wq; dst=wqkv_t;               N=1024; stride=1024; nx=32;  }
    else if (b < 1280) { b-=1024; src=wk; dst=wqkv_t+1024*1024; N=256; stride=1024; nx=8; }
    else if (b < 1536) { b-=1280; src=wv; dst=wqkv_t+1280*1024; N=256; stride=1024; nx=8; }
    else if (b < 2560) { b-=1536; src=wo; dst=wo_t;        N=1024; stride=1024; nx=32;  }
    else if (b < 6656) { b-=2560; src=w1; dst=w1_t;        N=4096; stride=1024; nx=128; }
    else               { b-=6656; src=w2; dst=w2_t;        N=1024; stride=4096; nx=32;  }
    int n0 = (b % nx)*32, k0 = (b / nx)*32;
    int tx = threadIdx.x & 31, ty = threadIdx.x >> 5;
    #pragma unroll
    for (int i = 0; i < 4; ++i)
      t[ty*4+i][tx] = src[(size_t)(k0+ty*4+i)*N + n0 + tx];
    __syncthreads();
    #pragma unroll
    for (int i = 0; i < 4; ++i)
      dst[(size_t)(n0+ty*4+i)*stride + k0 + tx] = __float2bfloat16(t[tx][ty*4+i]);
  } else if (blockIdx.x < 10752 + MROWS){
    __shared__ float sm[5];
    size_t row = blockIdx.x - 10752;
    const float4* xr = (const float4*)(x + row * DMODEL);
    float4 v = xr[threadIdx.x];
    float ss = v.x*v.x + v.y*v.y + v.z*v.z + v.w*v.w;
    #pragma unroll
    for (int off = 32; off; off >>= 1) ss += __shfl_down(ss, off);
    if ((threadIdx.x & 63) == 0) sm[threadIdx.x >> 6] = ss;
    __syncthreads();
    if (threadIdx.x == 0) sm[4] = rsqrtf((sm[0]+sm[1]+sm[2]+sm[3]) * (1.0f/DMODEL) + EPS);
    __syncthreads();
    float r = sm[4];
    float4 wv4 = ((const float4*)n1w)[threadIdx.x];
    ushort4 ob;
    ob.x = f2bf(v.x*r*wv4.x); ob.y = f2bf(v.y*r*wv4.y);
    ob.z = f2bf(v.z*r*wv4.z); ob.w = f2bf(v.w*r*wv4.w);
    ((ushort4*)(h + row * DMODEL))[threadIdx.x] = ob;
  } else {
    // RoPE cos/sin table: [S_LEN][32] each (f32)
    int idx = (blockIdx.x - (10752 + MROWS))*256 + threadIdx.x;   // 0..65535
    int s = idx >> 5, i = idx & 31;
    float invf = powf(10000.0f, -((float)(2*i)) * (1.0f/64.0f));
    float c, sn;
    sincosf((float)s * invf, &sn, &c);
    ctab[s*32 + i] = c;
    stab[s*32 + i] = sn;
  }
}

// ---------------- bf16 MFMA GEMM, 128x128 ----------------------------------
// C[M,N] = A[M,K] @ Wt[N,K]^T. 128x128 tile, BK=64, 4 waves (2x2), 4x4 16x16.
// R8 config (measured best): full-line staging + 2-D XCD swizzle;
// DB=true (2-phase dbuf) for K<=1024 GEMMs, DB=false for MLP-down.
// Full-line staging: lane l -> row (l>>3), k-chunk ((l&7) ^ (l>>3)): 8 rows
// x 128B full lines per instruction, each line touched once. LDS linear
// [128][64]; read XOR (s*32+lc*8)^((lr&7)*8) (verified 0 conflicts, R8).
// EPI: 1 = +bias,gelu->bf16 ; 3 = raw bf16 partial -> Cb + z*MROWS*N
template<int EPI, bool DB>
__global__ __launch_bounds__(256) void mgemm_k(const __hip_bfloat16* __restrict__ A,
                                               const __hip_bfloat16* __restrict__ Wt,
                                               const float* __restrict__ bias,
                                               __hip_bfloat16* __restrict__ Cb,
                                               int N, int Kstride, int kLen, int sy){
  __shared__ __align__(16) __hip_bfloat16 As[DB?2:1][8192];   // [128][64] row-major
  __shared__ __align__(16) __hip_bfloat16 Bs[DB?2:1][8192];
  const int tid = threadIdx.x;
  const int w = tid >> 6, l = tid & 63;
  const int lr = l & 15, lc = l >> 4;        // fragment-read coords
  const int lr7 = lr & 7;
  const int rrow = l >> 3;                   // staging: row within 8-group
  const int kch  = (l & 7) ^ rrow;           // staging: XOR-permuted k-chunk

  // ---- 2-D XCD-locality block mapping (R7) ----
  const unsigned gx = gridDim.x, gy = gridDim.y;
  unsigned hb  = (blockIdx.z * gy + blockIdx.y) * gx + blockIdx.x;
  unsigned xcd = hb & 7u;
  unsigned i   = hb >> 3;
  unsigned cgPerX = (gx * gridDim.z) >> 3;
  unsigned stSz = cgPerX * (unsigned)sy;
  unsigned st  = i / stSz, rr2 = i % stSz;
  unsigned cgl = rr2 % cgPerX, yy = rr2 / cgPerX;
  unsigned byi = st * (unsigned)sy + yy;
  unsigned cg  = xcd * cgPerX + cgl;
  unsigned bxi = cg % gx;
  unsigned bzi = cg / gx;

  const int bm = byi * 128, bn = bxi * 128;
  const int wm = (w >> 1) * 64, wn = (w & 1) * 64;
  const int kOff = bzi * kLen;

  // staging base pointers: wave w stages rows 32w..32w+31 of both tiles
  const __hip_bfloat16* Ag = A  + (size_t)(bm + 32*w + rrow)*Kstride + kOff + kch*8;
  const __hip_bfloat16* Bg = Wt + (size_t)(bn + 32*w + rrow)*Kstride + kOff + kch*8;

  f4_t acc[4][4] = {};

  auto stage = [&](int buf, int k0){
    #pragma unroll
    for (int ii = 0; ii < 4; ++ii){
      __builtin_amdgcn_global_load_lds((const AS1 void*)(Ag + (size_t)(8*ii)*Kstride + k0),
                                       (AS3 void*)(&As[buf][w*2048 + ii*512 + l*8]), 16, 0, 0);
      __builtin_amdgcn_global_load_lds((const AS1 void*)(Bg + (size_t)(8*ii)*Kstride + k0),
                                       (AS3 void*)(&Bs[buf][w*2048 + ii*512 + l*8]), 16, 0, 0);
    }
  };

  auto compute = [&](int buf){
    #pragma unroll
    for (int s = 0; s < 2; ++s){
      const int kx = (s*32 + lc*8) ^ (lr7*8);
      bf8_t af[4], bfr[4];
      #pragma unroll
      for (int mi = 0; mi < 4; ++mi)
        af[mi] = *(const bf8_t*)(&As[buf][(wm + mi*16 + lr)*64 + kx]);
      #pragma unroll
      for (int ni = 0; ni < 4; ++ni)
        bfr[ni] = *(const bf8_t*)(&Bs[buf][(wn + ni*16 + lr)*64 + kx]);
      #pragma unroll
      for (int mi = 0; mi < 4; ++mi)
        #pragma unroll
        for (int ni = 0; ni < 4; ++ni)
          acc[mi][ni] = __builtin_amdgcn_mfma_f32_16x16x32_bf16(af[mi], bfr[ni], acc[mi][ni], 0, 0, 0);
    }
  };

  if constexpr (DB){
    const int nt = kLen >> 6;
    stage(0, 0);
    asm volatile("s_waitcnt vmcnt(0)" ::: "memory");
    __builtin_amdgcn_s_barrier();
    int cur = 0;
    for (int t = 0; t < nt; ++t){
      if (t + 1 < nt) stage(cur ^ 1, (t + 1) << 6);
      compute(cur);
      asm volatile("s_waitcnt vmcnt(0)" ::: "memory");
      __builtin_amdgcn_s_barrier();
      cur ^= 1;
    }
  } else {
    for (int k0 = 0; k0 < kLen; k0 += 64){
      __syncthreads();
      stage(0, k0);
      __syncthreads();
      compute(0);
    }
  }

  __hip_bfloat16* Cp = (EPI == 3) ? (Cb + (size_t)bzi * ((size_t)MROWS * N)) : Cb;

  // C/D layout: col = lane&15 (=lr), row = (lane>>4)*4 + r (=lc*4+r)
  #pragma unroll
  for (int ni = 0; ni < 4; ++ni){
    int col = bn + wn + ni*16 + lr;
    float bb = (EPI == 3) ? 0.0f : bias[col];
    #pragma unroll
    for (int mi = 0; mi < 4; ++mi){
      #pragma unroll
      for (int r = 0; r < 4; ++r){
        int row = bm + wm + mi*16 + lc*4 + r;
        size_t off = (size_t)row * N + col;
        float v = acc[mi][ni][r] + bb;
        if (EPI == 1) Cp[off] = __float2bfloat16(gelu_f(v));
        else          Cp[off] = __float2bfloat16(v);
      }
    }
  }
}

// -------- split-K reduce: out = sum_bf16(partials) + bias + res (fp32) -------
template<int NS>
__global__ __launch_bounds__(256) void reduce_k(const unsigned short* __restrict__ P,
                                                const float* __restrict__ bias,
                                                const float* __restrict__ res,
                                                float* __restrict__ out, int N){
  size_t i = ((size_t)blockIdx.x*256 + threadIdx.x) * 4;
  int col = (int)(i % (size_t)N);
  size_t stride = (size_t)MROWS * N;
  float a0=0,a1=0,a2=0,a3=0;
  #pragma unroll
  for (int p = 0; p < NS; ++p){
    ushort4 u = *(const ushort4*)(P + p*stride + i);
    a0 += bf2f(u.x); a1 += bf2f(u.y); a2 += bf2f(u.z); a3 += bf2f(u.w);
  }
  float4 bb = *(const float4*)(bias + col);
  float4 r4 = *(const float4*)(res + i);
  float4 o = make_float4(a0+bb.x+r4.x, a1+bb.y+r4.y, a2+bb.z+r4.z, a3+bb.w+r4.w);
  *(float4*)(out + i) = o;
}

// ---- fused: wo split-K reduce (+bias+res) -> x1, then RMSNorm2 -> h_bf ------
template<int NS>
__global__ __launch_bounds__(256) void redn_k(const unsigned short* __restrict__ P,
                                              const float* __restrict__ bias,
                                              const float* __restrict__ res,
                                              const float* __restrict__ nw,
                                              float* __restrict__ x1,
                                              __hip_bfloat16* __restrict__ h){
  __shared__ float sm[5];
  size_t row = blockIdx.x;
  size_t i = row * DMODEL + threadIdx.x*4;
  size_t stride = (size_t)MROWS * DMODEL;
  float4 bb = *(const float4*)(bias + threadIdx.x*4);
  float4 r4 = *(const float4*)(res + i);
  float4 v = make_float4(bb.x+r4.x, bb.y+r4.y, bb.z+r4.z, bb.w+r4.w);
  #pragma unroll
  for (int p = 0; p < NS; ++p){
    ushort4 u = *(const ushort4*)(P + p*stride + i);
    v.x += bf2f(u.x); v.y += bf2f(u.y); v.z += bf2f(u.z); v.w += bf2f(u.w);
  }
  *(float4*)(x1 + i) = v;
  float ss = v.x*v.x + v.y*v.y + v.z*v.z + v.w*v.w;
  #pragma unroll
  for (int off = 32; off; off >>= 1) ss += __shfl_down(ss, off);
  if ((threadIdx.x & 63) == 0) sm[threadIdx.x >> 6] = ss;
  __syncthreads();
  if (threadIdx.x == 0) sm[4] = rsqrtf((sm[0]+sm[1]+sm[2]+sm[3]) * (1.0f/DMODEL) + EPS);
  __syncthreads();
  float r = sm[4];
  float4 wv = ((const float4*)nw)[threadIdx.x];
  ushort4 ob;
  ob.x = f2bf(v.x*r*wv.x); ob.y = f2bf(v.y*r*wv.y);
  ob.z = f2bf(v.z*r*wv.z); ob.w = f2bf(v.w*r*wv.w);
  ((ushort4*)(h + row * DMODEL))[threadIdx.x] = ob;
}

// -------- per-head RMSNorm + RoPE -> f16, reads qkv partial pair + bias ------
// R11: cos/sin from precomputed table (prep_k) instead of powf+sincosf.
__global__ __launch_bounds__(64) void rope2_k(const unsigned short* __restrict__ P,
                                              const float* __restrict__ bq, const float* __restrict__ bk,
                                              const float* __restrict__ qw, const float* __restrict__ kw,
                                              const float* __restrict__ ctab, const float* __restrict__ stab,
                                              _Float16* __restrict__ qo, _Float16* __restrict__ ko){
  const int s = blockIdx.x;
  const int y = blockIdx.y;                  // b*20 + r ; r<16 -> Q head r, else K head r-16
  const int b = y / 20, r0 = y % 20;
  const bool isQ = (r0 < 16);
  const int hh = isQ ? r0 : (r0 - 16);
  const int col0 = isQ ? hh*64 : 1024 + hh*64;
  const int lane = threadIdx.x;
  const size_t pstride = (size_t)MROWS * 1536;
  size_t off = ((size_t)s * BATCH + b) * 1536 + col0 + lane;
  float v = bf2f(P[off]) + bf2f(P[off + pstride])
          + (isQ ? bq[hh*64 + lane] : bk[hh*64 + lane]);
  float ss = v * v;
  #pragma unroll
  for (int m = 32; m; m >>= 1) ss += __shfl_xor(ss, m);
  float rr = rsqrtf(ss * (1.0f/64.0f) + EPS);
  v = v * rr * (isQ ? qw[lane] : kw[lane]);
  int i = lane & 31;
  float c  = ctab[s*32 + i];
  float sn = stab[s*32 + i];
  float partner = __shfl_xor(v, 32);
  float rh = (lane < 32) ? -partner : partner;
  float o = (v * c + rh * sn) * (isQ ? QSCALE : 1.0f);
  _Float16* outp = isQ ? (qo + (((size_t)b * NH  + hh) * S_LEN + s) * 64 + lane)
                       : (ko + (((size_t)b * NKV + hh) * S_LEN + s) * 64 + lane);
  *outp = (_Float16)o;
}

// -------- V extract from qkv partials -> Vt f16 [B*NKV][64][S] ---------------
__global__ __launch_bounds__(256) void vcast_k(const unsigned short* __restrict__ P,
                                               const float* __restrict__ bv,
                                               _Float16* __restrict__ Vt){
  __shared__ float t[64][65];
  const int s0 = blockIdx.x * 64;
  const int bkv = blockIdx.y;
  const int b = bkv >> 2, kv = bkv & 3;
  const int tid = threadIdx.x;
  const size_t pstride = (size_t)MROWS * 1536;
  #pragma unroll
  for (int i = 0; i < 16; ++i){
    int idx = tid + 256*i;
    int sl = idx >> 6, d = idx & 63;
    size_t off = ((size_t)(s0+sl)*BATCH + b)*1536 + 1280 + kv*64 + d;
    t[d][sl] = bf2f(P[off]) + bf2f(P[off + pstride]) + bv[kv*64 + d];
  }
  __syncthreads();
  #pragma unroll
  for (int i = 0; i < 16; ++i){
    int idx = tid + 256*i;
    int d = idx >> 6, sl = idx & 63;
    Vt[((size_t)bkv*64 + d)*S_LEN + s0 + sl] = (_Float16)t[d][sl];
  }
}

// ---------------- MFMA flash attention -------------------------------------
// R11: K/V LDS DOUBLE-BUFFER (the R2-proven GEMM dbuf schedule, never applied
// here). Old loop paid full L2 load latency every kt-step (barrier -> 16
// loads -> vmcnt(0)+barrier -> compute; measured ~4900 cyc/iter vs ~300 of
// work). Now stage(kt+1) is issued BEFORE compute(kt) so the latency hides
// under QK^T+softmax+PV. Softmax reverted to always-rescale (defer-max
// measured null-to-negative, R8 vs R10 A/B).
__global__ __launch_bounds__(256) void attn2_k(const _Float16* __restrict__ Q,
                                               const _Float16* __restrict__ K,
                                               const _Float16* __restrict__ Vt,
                                               __hip_bfloat16* __restrict__ AO){
  __shared__ __align__(16) _Float16 Ks[2][8*512];
  __shared__ __align__(16) _Float16 Vs[2][8*512];
  const int bh = blockIdx.x;
  const int qb = (gridDim.y - 1) - blockIdx.y;
  const int b = bh >> 4, h = bh & 15;
  const int kvh = h >> 2;
  const int tid = threadIdx.x;
  const int w = tid >> 6, l = tid & 63;
  const int lr = l & 15, quad = l >> 4;

  const _Float16* qp = Q + ((size_t)bh * S_LEN + qb*64 + w*16 + lr) * 64;
  h8_t qf0 = *(const h8_t*)(qp + quad*8);
  h8_t qf1 = *(const h8_t*)(qp + 32 + quad*8);

  const _Float16* kbase = K  + (size_t)(b*NKV + kvh) * S_LEN * 64;
  const _Float16* vbase = Vt + (size_t)(b*NKV + kvh) * 64 * S_LEN;

  f4_t Od[4] = {};
  float m_i = -3.0e38f, l_i = 0.0f;

  auto stage = [&](int buf, int kt){
    #pragma unroll
    for (int ii = 0; ii < 4; ++ii){
      int i = w*4 + ii;
      if (i < 8){
        int cc = i >> 1, dh = i & 1;
        const _Float16* src = kbase + (size_t)(kt*64 + cc*16 + lr)*64 + dh*32 + quad*8;
        __builtin_amdgcn_global_load_lds((const AS1 void*)src, (AS3 void*)(&Ks[buf][i*512] + l*8), 16, 0, 0);
      } else {
        int j = i - 8;
        int dd = j >> 1, cc32 = j & 1;
        const _Float16* src = vbase + (size_t)(dd*16 + lr)*S_LEN + kt*64 + cc32*32 + quad*8;
        __builtin_amdgcn_global_load_lds((const AS1 void*)src, (AS3 void*)(&Vs[buf][j*512] + l*8), 16, 0, 0);
      }
    }
  };

  // prologue: stage tile 0, publish
  stage(0, 0);
  asm volatile("s_waitcnt vmcnt(0)" ::: "memory");
  __builtin_amdgcn_s_barrier();
  int cur = 0;

  for (int kt = 0; kt <= qb; ++kt){
    // issue next K/V tile's loads — they fly under this tile's compute
    if (kt < qb) stage(cur ^ 1, kt + 1);

    const bool diag = (kt == qb);
    f4_t sc[4];
    #pragma unroll
    for (int nc2 = 0; nc2 < 4; ++nc2){
      if (diag && nc2 > w){
        sc[nc2][0] = -1.0e30f; sc[nc2][1] = -1.0e30f;
        sc[nc2][2] = -1.0e30f; sc[nc2][3] = -1.0e30f;
        continue;
      }
      f4_t a = {};
      h8_t k0 = *(const h8_t*)(&Ks[cur][(nc2*2+0)*512] + l*8);
      h8_t k1 = *(const h8_t*)(&Ks[cur][(nc2*2+1)*512] + l*8);
      a = __builtin_amdgcn_mfma_f32_16x16x32_f16(k0, qf0, a, 0, 0, 0);
      a = __builtin_amdgcn_mfma_f32_16x16x32_f16(k1, qf1, a, 0, 0, 0);
      if (diag && nc2 == w){
        #pragma unroll
        for (int r = 0; r < 4; ++r)
          if (quad*4 + r > lr) a[r] = -1.0e30f;
      }
      sc[nc2] = a;
    }

    float mx = sc[0][0];
    #pragma unroll
    for (int nc2 = 0; nc2 < 4; ++nc2)
      #pragma unroll
      for (int r = 0; r < 4; ++r) mx = fmaxf(mx, sc[nc2][r]);
    mx = fmaxf(mx, __shfl_xor(mx, 16));
    mx = fmaxf(mx, __shfl_xor(mx, 32));
    float nm = fmaxf(mx, m_i);
    float alpha = exp2_fast(m_i - nm);
    m_i = nm;
    float rs = 0.0f;
    h4_t pf[4];
    #pragma unroll
    for (int nc2 = 0; nc2 < 4; ++nc2)
      #pragma unroll
      for (int r = 0; r < 4; ++r){
        float e = exp2_fast(sc[nc2][r] - nm);
        rs += e;
        pf[nc2][r] = (_Float16)e;
      }
    rs += __shfl_xor(rs, 16);
    rs += __shfl_xor(rs, 32);
    l_i = l_i * alpha + rs;
    #pragma unroll
    for (int dd = 0; dd < 4; ++dd)
      #pragma unroll
      for (int r = 0; r < 4; ++r) Od[dd][r] *= alpha;

    #pragma unroll
    for (int dd = 0; dd < 4; ++dd)
      #pragma unroll
      for (int nc2 = 0; nc2 < 4; ++nc2){
        if (diag && nc2 > w) continue;
        h4_t vf = *(const h4_t*)(&Vs[cur][(dd*2 + (nc2>>1))*512]
                                 + (((nc2&1)*2 + (quad>>1))*16 + lr)*8 + (quad&1)*4);
        Od[dd] = MFMA16(vf, pf[nc2], Od[dd]);
      }

    // drain the (overlapped) next-tile loads, publish buffer swap
    asm volatile("s_waitcnt vmcnt(0)" ::: "memory");
    __builtin_amdgcn_s_barrier();
    cur ^= 1;
  }

  float inv = 1.0f / l_i;
  #pragma unroll
  for (int dd = 0; dd < 4; ++dd){
    ushort4 w4;
    w4.x = f2bf(Od[dd][0]*inv); w4.y = f2bf(Od[dd][1]*inv);
    w4.z = f2bf(Od[dd][2]*inv); w4.w = f2bf(Od[dd][3]*inv);
    size_t sg = (size_t)qb*64 + w*16 + lr;
    *(ushort4*)(AO + (sg*BATCH + b)*DMODEL + h*64 + dd*16 + quad*4) = w4;
  }
}

extern "C" void kernel_launch(void* const* d_in, const int* in_sizes, int n_in,
                              void* d_out, int out_size, void* d_ws, size_t ws_size,
                              hipStream_t stream){
  const float* x   = (const float*)d_in[0];
  const float* n1w = (const float*)d_in[1];
  const float* wq  = (const float*)d_in[2];
  const float* bq  = (const float*)d_in[3];
  const float* wk  = (const float*)d_in[4];
  const float* bk  = (const float*)d_in[5];
  const float* wv  = (const float*)d_in[6];
  const float* bv  = (const float*)d_in[7];
  const float* qnw = (const float*)d_in[8];
  const float* knw = (const float*)d_in[9];
  const float* wo  = (const float*)d_in[10];
  const float* bo  = (const float*)d_in[11];
  const float* n2w = (const float*)d_in[12];
  const float* w1  = (const float*)d_in[13];
  const float* b1  = (const float*)d_in[14];
  const float* w2  = (const float*)d_in[15];
  const float* b2  = (const float*)d_in[16];
  float* out = (float*)d_out;

  char* p = (char*)d_ws;
  auto carve = [&](size_t bytes)->char*{ char* r = p; p += (bytes + 255) & ~(size_t)255; return r; };
  __hip_bfloat16* h_bf   = (__hip_bfloat16*)carve((size_t)MROWS*DMODEL*2);
  __hip_bfloat16* ao_bf  = (__hip_bfloat16*)carve((size_t)MROWS*DMODEL*2);
  __hip_bfloat16* mid_bf = (__hip_bfloat16*)carve((size_t)MROWS*4096*2);
  __hip_bfloat16* wqkv_t = (__hip_bfloat16*)carve((size_t)1536*1024*2);
  __hip_bfloat16* wo_t   = (__hip_bfloat16*)carve((size_t)1024*1024*2);
  __hip_bfloat16* w1_t   = (__hip_bfloat16*)carve((size_t)4096*1024*2);
  __hip_bfloat16* w2_t   = (__hip_bfloat16*)carve((size_t)1024*4096*2);
  // shared scratch: qkv split-2 partials (25.2 MB) early, then wo/w2 split-2
  // partials (16.8 MB). Lifetimes disjoint (qkv_p dead after rope2/vcast).
  char* scratch = carve((size_t)2*MROWS*1536*2);
  __hip_bfloat16* qkv_p = (__hip_bfloat16*)scratch;   // 2*MROWS*1536*2
  __hip_bfloat16* ps    = (__hip_bfloat16*)scratch;   // 2*MROWS*1024*2 fits
  _Float16* q_f  = (_Float16*)carve((size_t)BATCH*NH *S_LEN*64*2);
  _Float16* k_f  = (_Float16*)carve((size_t)BATCH*NKV*S_LEN*64*2);
  _Float16* vt_f = (_Float16*)carve((size_t)BATCH*NKV*64*S_LEN*2);
  float* x1   = (float*)carve((size_t)MROWS*DMODEL*4);
  float* ctab = (float*)carve((size_t)S_LEN*32*4);
  float* stab = (float*)carve((size_t)S_LEN*32*4);

  // weight prep + rmsnorm1 + rope table in one launch
  prep_k<<<10752 + MROWS + 256, 256, 0, stream>>>(wq, wk, wv, wo, w1, w2,
                                                  wqkv_t, wo_t, w1_t, w2_t, x, n1w, h_bf,
                                                  ctab, stab);

  // QKV: M=4096 N=1536 K=1024, split-K=2 (768 blocks), dbuf + 2D swizzle
  mgemm_k<3,true><<<dim3(12, 32, 2), 256, 0, stream>>>(h_bf, wqkv_t, nullptr, qkv_p, 1536, 1024, 512, 8);

  rope2_k<<<dim3(S_LEN, BATCH*20), 64, 0, stream>>>((const unsigned short*)qkv_p, bq, bk, qnw, knw, ctab, stab, q_f, k_f);
  vcast_k<<<dim3(S_LEN/64, BATCH*NKV), 256, 0, stream>>>((const unsigned short*)qkv_p, bv, vt_f);
  attn2_k<<<dim3(BATCH*NH, S_LEN/64), 256, 0, stream>>>(q_f, k_f, vt_f, ao_bf);

  // O-proj: M=4096 N=1024 K=1024, split-K=2 (512 blocks), dbuf + 2D swizzle
  mgemm_k<3,true><<<dim3(8, 32, 2), 256, 0, stream>>>(ao_bf, wo_t, nullptr, ps, 1024, 1024, 512, 8);
  // fused: reduce(+bias+res) -> x1 AND rmsnorm2 -> h_bf
  redn_k<2><<<MROWS, 256, 0, stream>>>((const unsigned short*)ps, bo, x, n2w, x1, h_bf);

  // MLP up: M=4096 N=4096 K=1024 (1024 blocks), dbuf + 2D swizzle, gelu fused
  mgemm_k<1,true><<<dim3(32, 32, 1), 256, 0, stream>>>(h_bf, w1_t, b1, mid_bf, 4096, 1024, 1024, 8);

  // MLP down: M=4096 N=1024 K=4096, split-K=2 (512 blocks), single-buf + 2D swizzle
  mgemm_k<3,false><<<dim3(8, 32, 2), 256, 0, stream>>>(mid_bf, w2_t, nullptr, ps, 1024, 4096, 2048, 4);
  reduce_k<2><<<4096, 256, 0, stream>>>((const unsigned short*)ps, b2, x1, out, 1024);
}

// Round 12
// 349.674 us; speedup vs baseline: 1.0998x; 1.0109x over previous
//
#include <hip/hip_runtime.h>
#include <hip/hip_bf16.h>
#include <math.h>

#define S_LEN 2048
#define BATCH 2
#define DMODEL 1024
#define NH 16
#define NKV 4
#define HDIM 64
#define EPS 1e-5f
#define MROWS (S_LEN*BATCH)  // 4096
#define QSCALE (0.03125f * 1.44269504088896f)

#define AS1 __attribute__((address_space(1)))
#define AS3 __attribute__((address_space(3)))

typedef __attribute__((ext_vector_type(8))) short bf8_t;
typedef __attribute__((ext_vector_type(4))) float f4_t;
typedef _Float16 __attribute__((ext_vector_type(8))) h8_t;
typedef _Float16 __attribute__((ext_vector_type(4))) h4_t;

#define MFMA16(a,b,c) __builtin_amdgcn_mfma_f32_16x16x16f16(a,b,c,0,0,0)

__device__ __forceinline__ float exp2_fast(float x){ return __builtin_exp2f(x); }

__device__ __forceinline__ unsigned short f2bf(float f){
  __hip_bfloat16 b = __float2bfloat16(f);
  return __builtin_bit_cast(unsigned short, b);
}
__device__ __forceinline__ float bf2f(unsigned short u){
  return __builtin_bit_cast(float, (unsigned)u << 16);
}
__device__ __forceinline__ float gelu_f(float x){
  return 0.5f * x * (1.0f + erff(x * 0.7071067811865475f));
}

// -- prep: weight transposes (0..10751) + RMSNorm1 (..14847) + RoPE table ----
__global__ __launch_bounds__(256) void prep_k(const float* __restrict__ wq, const float* __restrict__ wk,
                                              const float* __restrict__ wv, const float* __restrict__ wo,
                                              const float* __restrict__ w1, const float* __restrict__ w2,
                                              __hip_bfloat16* __restrict__ wqkv_t, __hip_bfloat16* __restrict__ wo_t,
                                              __hip_bfloat16* __restrict__ w1_t,   __hip_bfloat16* __restrict__ w2_t,
                                              const float* __restrict__ x, const float* __restrict__ n1w,
                                              __hip_bfloat16* __restrict__ h,
                                              float* __restrict__ ctab, float* __restrict__ stab){
  if (blockIdx.x < 10752){
    __shared__ float t[32][33];
    int b = blockIdx.x;
    const float* src; __hip_bfloat16* dst; int N, stride, nx;
    if (b < 1024)      { src=wq; dst=wqkv_t;               N=1024; stride=1024; nx=32;  }
    else if (b < 1280) { b-=1024; src=wk; dst=wqkv_t+1024*1024; N=256; stride=1024; nx=8; }
    else if (b < 1536) { b-=1280; src=wv; dst=wqkv_t+1280*1024; N=256; stride=1024; nx=8; }
    else if (b < 2560) { b-=1536; src=wo; dst=wo_t;        N=1024; stride=1024; nx=32;  }
    else if (b < 6656) { b-=2560; src=w1; dst=w1_t;        N=4096; stride=1024; nx=128; }
    else               { b-=6656; src=w2; dst=w2_t;        N=1024; stride=4096; nx=32;  }
    int n0 = (b % nx)*32, k0 = (b / nx)*32;
    int tx = threadIdx.x & 31, ty = threadIdx.x >> 5;
    #pragma unroll
    for (int i = 0; i < 4; ++i)
      t[ty*4+i][tx] = src[(size_t)(k0+ty*4+i)*N + n0 + tx];
    __syncthreads();
    #pragma unroll
    for (int i = 0; i < 4; ++i)
      dst[(size_t)(n0+ty*4+i)*stride + k0 + tx] = __float2bfloat16(t[tx][ty*4+i]);
  } else if (blockIdx.x < 10752 + MROWS){
    __shared__ float sm[5];
    size_t row = blockIdx.x - 10752;
    const float4* xr = (const float4*)(x + row * DMODEL);
    float4 v = xr[threadIdx.x];
    float ss = v.x*v.x + v.y*v.y + v.z*v.z + v.w*v.w;
    #pragma unroll
    for (int off = 32; off; off >>= 1) ss += __shfl_down(ss, off);
    if ((threadIdx.x & 63) == 0) sm[threadIdx.x >> 6] = ss;
    __syncthreads();
    if (threadIdx.x == 0) sm[4] = rsqrtf((sm[0]+sm[1]+sm[2]+sm[3]) * (1.0f/DMODEL) + EPS);
    __syncthreads();
    float r = sm[4];
    float4 wv4 = ((const float4*)n1w)[threadIdx.x];
    ushort4 ob;
    ob.x = f2bf(v.x*r*wv4.x); ob.y = f2bf(v.y*r*wv4.y);
    ob.z = f2bf(v.z*r*wv4.z); ob.w = f2bf(v.w*r*wv4.w);
    ((ushort4*)(h + row * DMODEL))[threadIdx.x] = ob;
  } else {
    // RoPE cos/sin table: [S_LEN][32] each (f32)
    int idx = (blockIdx.x - (10752 + MROWS))*256 + threadIdx.x;   // 0..65535
    int s = idx >> 5, i = idx & 31;
    float invf = powf(10000.0f, -((float)(2*i)) * (1.0f/64.0f));
    float c, sn;
    sincosf((float)s * invf, &sn, &c);
    ctab[s*32 + i] = c;
    stab[s*32 + i] = sn;
  }
}

// ---------------- bf16 MFMA GEMM, 128x128 ----------------------------------
// C[M,N] = A[M,K] @ Wt[N,K]^T. 128x128 tile, BK=64, 4 waves (2x2), 4x4 16x16.
// R8 config (measured best): full-line staging + 2-D XCD swizzle;
// DB=true (2-phase dbuf) for K<=1024 GEMMs, DB=false for MLP-down.
// FROZEN since R10 (R11 showed MLP-up 65->112us with identical code; dur
// scaled exactly with hbm_gbps (1.72x both) -> suspected container/memory-
// clock variance, re-measuring this round with code held constant).
// EPI: 1 = +bias,gelu->bf16 ; 3 = raw bf16 partial -> Cb + z*MROWS*N
template<int EPI, bool DB>
__global__ __launch_bounds__(256) void mgemm_k(const __hip_bfloat16* __restrict__ A,
                                               const __hip_bfloat16* __restrict__ Wt,
                                               const float* __restrict__ bias,
                                               __hip_bfloat16* __restrict__ Cb,
                                               int N, int Kstride, int kLen, int sy){
  __shared__ __align__(16) __hip_bfloat16 As[DB?2:1][8192];   // [128][64] row-major
  __shared__ __align__(16) __hip_bfloat16 Bs[DB?2:1][8192];
  const int tid = threadIdx.x;
  const int w = tid >> 6, l = tid & 63;
  const int lr = l & 15, lc = l >> 4;        // fragment-read coords
  const int lr7 = lr & 7;
  const int rrow = l >> 3;                   // staging: row within 8-group
  const int kch  = (l & 7) ^ rrow;           // staging: XOR-permuted k-chunk

  // ---- 2-D XCD-locality block mapping (R7) ----
  const unsigned gx = gridDim.x, gy = gridDim.y;
  unsigned hb  = (blockIdx.z * gy + blockIdx.y) * gx + blockIdx.x;
  unsigned xcd = hb & 7u;
  unsigned i   = hb >> 3;
  unsigned cgPerX = (gx * gridDim.z) >> 3;
  unsigned stSz = cgPerX * (unsigned)sy;
  unsigned st  = i / stSz, rr2 = i % stSz;
  unsigned cgl = rr2 % cgPerX, yy = rr2 / cgPerX;
  unsigned byi = st * (unsigned)sy + yy;
  unsigned cg  = xcd * cgPerX + cgl;
  unsigned bxi = cg % gx;
  unsigned bzi = cg / gx;

  const int bm = byi * 128, bn = bxi * 128;
  const int wm = (w >> 1) * 64, wn = (w & 1) * 64;
  const int kOff = bzi * kLen;

  // staging base pointers: wave w stages rows 32w..32w+31 of both tiles
  const __hip_bfloat16* Ag = A  + (size_t)(bm + 32*w + rrow)*Kstride + kOff + kch*8;
  const __hip_bfloat16* Bg = Wt + (size_t)(bn + 32*w + rrow)*Kstride + kOff + kch*8;

  f4_t acc[4][4] = {};

  auto stage = [&](int buf, int k0){
    #pragma unroll
    for (int ii = 0; ii < 4; ++ii){
      __builtin_amdgcn_global_load_lds((const AS1 void*)(Ag + (size_t)(8*ii)*Kstride + k0),
                                       (AS3 void*)(&As[buf][w*2048 + ii*512 + l*8]), 16, 0, 0);
      __builtin_amdgcn_global_load_lds((const AS1 void*)(Bg + (size_t)(8*ii)*Kstride + k0),
                                       (AS3 void*)(&Bs[buf][w*2048 + ii*512 + l*8]), 16, 0, 0);
    }
  };

  auto compute = [&](int buf){
    #pragma unroll
    for (int s = 0; s < 2; ++s){
      const int kx = (s*32 + lc*8) ^ (lr7*8);
      bf8_t af[4], bfr[4];
      #pragma unroll
      for (int mi = 0; mi < 4; ++mi)
        af[mi] = *(const bf8_t*)(&As[buf][(wm + mi*16 + lr)*64 + kx]);
      #pragma unroll
      for (int ni = 0; ni < 4; ++ni)
        bfr[ni] = *(const bf8_t*)(&Bs[buf][(wn + ni*16 + lr)*64 + kx]);
      #pragma unroll
      for (int mi = 0; mi < 4; ++mi)
        #pragma unroll
        for (int ni = 0; ni < 4; ++ni)
          acc[mi][ni] = __builtin_amdgcn_mfma_f32_16x16x32_bf16(af[mi], bfr[ni], acc[mi][ni], 0, 0, 0);
    }
  };

  if constexpr (DB){
    const int nt = kLen >> 6;
    stage(0, 0);
    asm volatile("s_waitcnt vmcnt(0)" ::: "memory");
    __builtin_amdgcn_s_barrier();
    int cur = 0;
    for (int t = 0; t < nt; ++t){
      if (t + 1 < nt) stage(cur ^ 1, (t + 1) << 6);
      compute(cur);
      asm volatile("s_waitcnt vmcnt(0)" ::: "memory");
      __builtin_amdgcn_s_barrier();
      cur ^= 1;
    }
  } else {
    for (int k0 = 0; k0 < kLen; k0 += 64){
      __syncthreads();
      stage(0, k0);
      __syncthreads();
      compute(0);
    }
  }

  __hip_bfloat16* Cp = (EPI == 3) ? (Cb + (size_t)bzi * ((size_t)MROWS * N)) : Cb;

  // C/D layout: col = lane&15 (=lr), row = (lane>>4)*4 + r (=lc*4+r)
  #pragma unroll
  for (int ni = 0; ni < 4; ++ni){
    int col = bn + wn + ni*16 + lr;
    float bb = (EPI == 3) ? 0.0f : bias[col];
    #pragma unroll
    for (int mi = 0; mi < 4; ++mi){
      #pragma unroll
      for (int r = 0; r < 4; ++r){
        int row = bm + wm + mi*16 + lc*4 + r;
        size_t off = (size_t)row * N + col;
        float v = acc[mi][ni][r] + bb;
        if (EPI == 1) Cp[off] = __float2bfloat16(gelu_f(v));
        else          Cp[off] = __float2bfloat16(v);
      }
    }
  }
}

// -------- split-K reduce: out = sum_bf16(partials) + bias + res (fp32) -------
template<int NS>
__global__ __launch_bounds__(256) void reduce_k(const unsigned short* __restrict__ P,
                                                const float* __restrict__ bias,
                                                const float* __restrict__ res,
                                                float* __restrict__ out, int N){
  size_t i = ((size_t)blockIdx.x*256 + threadIdx.x) * 4;
  int col = (int)(i % (size_t)N);
  size_t stride = (size_t)MROWS * N;
  float a0=0,a1=0,a2=0,a3=0;
  #pragma unroll
  for (int p = 0; p < NS; ++p){
    ushort4 u = *(const ushort4*)(P + p*stride + i);
    a0 += bf2f(u.x); a1 += bf2f(u.y); a2 += bf2f(u.z); a3 += bf2f(u.w);
  }
  float4 bb = *(const float4*)(bias + col);
  float4 r4 = *(const float4*)(res + i);
  float4 o = make_float4(a0+bb.x+r4.x, a1+bb.y+r4.y, a2+bb.z+r4.z, a3+bb.w+r4.w);
  *(float4*)(out + i) = o;
}

// ---- fused: wo split-K reduce (+bias+res) -> x1, then RMSNorm2 -> h_bf ------
template<int NS>
__global__ __launch_bounds__(256) void redn_k(const unsigned short* __restrict__ P,
                                              const float* __restrict__ bias,
                                              const float* __restrict__ res,
                                              const float* __restrict__ nw,
                                              float* __restrict__ x1,
                                              __hip_bfloat16* __restrict__ h){
  __shared__ float sm[5];
  size_t row = blockIdx.x;
  size_t i = row * DMODEL + threadIdx.x*4;
  size_t stride = (size_t)MROWS * DMODEL;
  float4 bb = *(const float4*)(bias + threadIdx.x*4);
  float4 r4 = *(const float4*)(res + i);
  float4 v = make_float4(bb.x+r4.x, bb.y+r4.y, bb.z+r4.z, bb.w+r4.w);
  #pragma unroll
  for (int p = 0; p < NS; ++p){
    ushort4 u = *(const ushort4*)(P + p*stride + i);
    v.x += bf2f(u.x); v.y += bf2f(u.y); v.z += bf2f(u.z); v.w += bf2f(u.w);
  }
  *(float4*)(x1 + i) = v;
  float ss = v.x*v.x + v.y*v.y + v.z*v.z + v.w*v.w;
  #pragma unroll
  for (int off = 32; off; off >>= 1) ss += __shfl_down(ss, off);
  if ((threadIdx.x & 63) == 0) sm[threadIdx.x >> 6] = ss;
  __syncthreads();
  if (threadIdx.x == 0) sm[4] = rsqrtf((sm[0]+sm[1]+sm[2]+sm[3]) * (1.0f/DMODEL) + EPS);
  __syncthreads();
  float r = sm[4];
  float4 wv = ((const float4*)nw)[threadIdx.x];
  ushort4 ob;
  ob.x = f2bf(v.x*r*wv.x); ob.y = f2bf(v.y*r*wv.y);
  ob.z = f2bf(v.z*r*wv.z); ob.w = f2bf(v.w*r*wv.w);
  ((ushort4*)(h + row * DMODEL))[threadIdx.x] = ob;
}

// -------- per-head RMSNorm + RoPE -> f16, reads qkv partial pair + bias ------
// R12: 256-thread blocks, 4 wave-rows each (was 64-thread blocks; pure
// launch-count reduction 40960->10240, wave-local semantics unchanged).
// cos/sin from precomputed table (R11).
__global__ __launch_bounds__(256) void rope2_k(const unsigned short* __restrict__ P,
                                              const float* __restrict__ bq, const float* __restrict__ bk,
                                              const float* __restrict__ qw, const float* __restrict__ kw,
                                              const float* __restrict__ ctab, const float* __restrict__ stab,
                                              _Float16* __restrict__ qo, _Float16* __restrict__ ko){
  const int s = blockIdx.x;
  const int y = blockIdx.y*4 + (threadIdx.x >> 6);   // b*20 + r ; r<16 -> Q head r, else K head r-16
  const int b = y / 20, r0 = y % 20;
  const bool isQ = (r0 < 16);
  const int hh = isQ ? r0 : (r0 - 16);
  const int col0 = isQ ? hh*64 : 1024 + hh*64;
  const int lane = threadIdx.x & 63;
  const size_t pstride = (size_t)MROWS * 1536;
  size_t off = ((size_t)s * BATCH + b) * 1536 + col0 + lane;
  float v = bf2f(P[off]) + bf2f(P[off + pstride])
          + (isQ ? bq[hh*64 + lane] : bk[hh*64 + lane]);
  float ss = v * v;
  #pragma unroll
  for (int m = 32; m; m >>= 1) ss += __shfl_xor(ss, m);
  float rr = rsqrtf(ss * (1.0f/64.0f) + EPS);
  v = v * rr * (isQ ? qw[lane] : kw[lane]);
  int i = lane & 31;
  float c  = ctab[s*32 + i];
  float sn = stab[s*32 + i];
  float partner = __shfl_xor(v, 32);
  float rh = (lane < 32) ? -partner : partner;
  float o = (v * c + rh * sn) * (isQ ? QSCALE : 1.0f);
  _Float16* outp = isQ ? (qo + (((size_t)b * NH  + hh) * S_LEN + s) * 64 + lane)
                       : (ko + (((size_t)b * NKV + hh) * S_LEN + s) * 64 + lane);
  *outp = (_Float16)o;
}

// -------- V extract from qkv partials -> Vt f16 [B*NKV][64][S] ---------------
__global__ __launch_bounds__(256) void vcast_k(const unsigned short* __restrict__ P,
                                               const float* __restrict__ bv,
                                               _Float16* __restrict__ Vt){
  __shared__ float t[64][65];
  const int s0 = blockIdx.x * 64;
  const int bkv = blockIdx.y;
  const int b = bkv >> 2, kv = bkv & 3;
  const int tid = threadIdx.x;
  const size_t pstride = (size_t)MROWS * 1536;
  #pragma unroll
  for (int i = 0; i < 16; ++i){
    int idx = tid + 256*i;
    int sl = idx >> 6, d = idx & 63;
    size_t off = ((size_t)(s0+sl)*BATCH + b)*1536 + 1280 + kv*64 + d;
    t[d][sl] = bf2f(P[off]) + bf2f(P[off + pstride]) + bv[kv*64 + d];
  }
  __syncthreads();
  #pragma unroll
  for (int i = 0; i < 16; ++i){
    int idx = tid + 256*i;
    int d = idx >> 6, sl = idx & 63;
    Vt[((size_t)bkv*64 + d)*S_LEN + s0 + sl] = (_Float16)t[d][sl];
  }
}

// ---------------- MFMA flash attention -------------------------------------
// K/V LDS double-buffer (R11, kept): stage(kt+1) issued BEFORE compute(kt)
// so L2 load latency hides under QK^T+softmax+PV. Always-rescale softmax
// (defer-max measured null-to-negative in R8-vs-R10 A/B).
__global__ __launch_bounds__(256) void attn2_k(const _Float16* __restrict__ Q,
                                               const _Float16* __restrict__ K,
                                               const _Float16* __restrict__ Vt,
                                               __hip_bfloat16* __restrict__ AO){
  __shared__ __align__(16) _Float16 Ks[2][8*512];
  __shared__ __align__(16) _Float16 Vs[2][8*512];
  const int bh = blockIdx.x;
  const int qb = (gridDim.y - 1) - blockIdx.y;
  const int b = bh >> 4, h = bh & 15;
  const int kvh = h >> 2;
  const int tid = threadIdx.x;
  const int w = tid >> 6, l = tid & 63;
  const int lr = l & 15, quad = l >> 4;

  const _Float16* qp = Q + ((size_t)bh * S_LEN + qb*64 + w*16 + lr) * 64;
  h8_t qf0 = *(const h8_t*)(qp + quad*8);
  h8_t qf1 = *(const h8_t*)(qp + 32 + quad*8);

  const _Float16* kbase = K  + (size_t)(b*NKV + kvh) * S_LEN * 64;
  const _Float16* vbase = Vt + (size_t)(b*NKV + kvh) * 64 * S_LEN;

  f4_t Od[4] = {};
  float m_i = -3.0e38f, l_i = 0.0f;

  auto stage = [&](int buf, int kt){
    #pragma unroll
    for (int ii = 0; ii < 4; ++ii){
      int i = w*4 + ii;
      if (i < 8){
        int cc = i >> 1, dh = i & 1;
        const _Float16* src = kbase + (size_t)(kt*64 + cc*16 + lr)*64 + dh*32 + quad*8;
        __builtin_amdgcn_global_load_lds((const AS1 void*)src, (AS3 void*)(&Ks[buf][i*512] + l*8), 16, 0, 0);
      } else {
        int j = i - 8;
        int dd = j >> 1, cc32 = j & 1;
        const _Float16* src = vbase + (size_t)(dd*16 + lr)*S_LEN + kt*64 + cc32*32 + quad*8;
        __builtin_amdgcn_global_load_lds((const AS1 void*)src, (AS3 void*)(&Vs[buf][j*512] + l*8), 16, 0, 0);
      }
    }
  };

  // prologue: stage tile 0, publish
  stage(0, 0);
  asm volatile("s_waitcnt vmcnt(0)" ::: "memory");
  __builtin_amdgcn_s_barrier();
  int cur = 0;

  for (int kt = 0; kt <= qb; ++kt){
    // issue next K/V tile's loads — they fly under this tile's compute
    if (kt < qb) stage(cur ^ 1, kt + 1);

    const bool diag = (kt == qb);
    f4_t sc[4];
    #pragma unroll
    for (int nc2 = 0; nc2 < 4; ++nc2){
      if (diag && nc2 > w){
        sc[nc2][0] = -1.0e30f; sc[nc2][1] = -1.0e30f;
        sc[nc2][2] = -1.0e30f; sc[nc2][3] = -1.0e30f;
        continue;
      }
      f4_t a = {};
      h8_t k0 = *(const h8_t*)(&Ks[cur][(nc2*2+0)*512] + l*8);
      h8_t k1 = *(const h8_t*)(&Ks[cur][(nc2*2+1)*512] + l*8);
      a = __builtin_amdgcn_mfma_f32_16x16x32_f16(k0, qf0, a, 0, 0, 0);
      a = __builtin_amdgcn_mfma_f32_16x16x32_f16(k1, qf1, a, 0, 0, 0);
      if (diag && nc2 == w){
        #pragma unroll
        for (int r = 0; r < 4; ++r)
          if (quad*4 + r > lr) a[r] = -1.0e30f;
      }
      sc[nc2] = a;
    }

    float mx = sc[0][0];
    #pragma unroll
    for (int nc2 = 0; nc2 < 4; ++nc2)
      #pragma unroll
      for (int r = 0; r < 4; ++r) mx = fmaxf(mx, sc[nc2][r]);
    mx = fmaxf(mx, __shfl_xor(mx, 16));
    mx = fmaxf(mx, __shfl_xor(mx, 32));
    float nm = fmaxf(mx, m_i);
    float alpha = exp2_fast(m_i - nm);
    m_i = nm;
    float rs = 0.0f;
    h4_t pf[4];
    #pragma unroll
    for (int nc2 = 0; nc2 < 4; ++nc2)
      #pragma unroll
      for (int r = 0; r < 4; ++r){
        float e = exp2_fast(sc[nc2][r] - nm);
        rs += e;
        pf[nc2][r] = (_Float16)e;
      }
    rs += __shfl_xor(rs, 16);
    rs += __shfl_xor(rs, 32);
    l_i = l_i * alpha + rs;
    #pragma unroll
    for (int dd = 0; dd < 4; ++dd)
      #pragma unroll
      for (int r = 0; r < 4; ++r) Od[dd][r] *= alpha;

    #pragma unroll
    for (int dd = 0; dd < 4; ++dd)
      #pragma unroll
      for (int nc2 = 0; nc2 < 4; ++nc2){
        if (diag && nc2 > w) continue;
        h4_t vf = *(const h4_t*)(&Vs[cur][(dd*2 + (nc2>>1))*512]
                                 + (((nc2&1)*2 + (quad>>1))*16 + lr)*8 + (quad&1)*4);
        Od[dd] = MFMA16(vf, pf[nc2], Od[dd]);
      }

    // drain the (overlapped) next-tile loads, publish buffer swap
    asm volatile("s_waitcnt vmcnt(0)" ::: "memory");
    __builtin_amdgcn_s_barrier();
    cur ^= 1;
  }

  float inv = 1.0f / l_i;
  #pragma unroll
  for (int dd = 0; dd < 4; ++dd){
    ushort4 w4;
    w4.x = f2bf(Od[dd][0]*inv); w4.y = f2bf(Od[dd][1]*inv);
    w4.z = f2bf(Od[dd][2]*inv); w4.w = f2bf(Od[dd][3]*inv);
    size_t sg = (size_t)qb*64 + w*16 + lr;
    *(ushort4*)(AO + (sg*BATCH + b)*DMODEL + h*64 + dd*16 + quad*4) = w4;
  }
}

extern "C" void kernel_launch(void* const* d_in, const int* in_sizes, int n_in,
                              void* d_out, int out_size, void* d_ws, size_t ws_size,
                              hipStream_t stream){
  const float* x   = (const float*)d_in[0];
  const float* n1w = (const float*)d_in[1];
  const float* wq  = (const float*)d_in[2];
  const float* bq  = (const float*)d_in[3];
  const float* wk  = (const float*)d_in[4];
  const float* bk  = (const float*)d_in[5];
  const float* wv  = (const float*)d_in[6];
  const float* bv  = (const float*)d_in[7];
  const float* qnw = (const float*)d_in[8];
  const float* knw = (const float*)d_in[9];
  const float* wo  = (const float*)d_in[10];
  const float* bo  = (const float*)d_in[11];
  const float* n2w = (const float*)d_in[12];
  const float* w1  = (const float*)d_in[13];
  const float* b1  = (const float*)d_in[14];
  const float* w2  = (const float*)d_in[15];
  const float* b2  = (const float*)d_in[16];
  float* out = (float*)d_out;

  char* p = (char*)d_ws;
  auto carve = [&](size_t bytes)->char*{ char* r = p; p += (bytes + 255) & ~(size_t)255; return r; };
  __hip_bfloat16* h_bf   = (__hip_bfloat16*)carve((size_t)MROWS*DMODEL*2);
  __hip_bfloat16* ao_bf  = (__hip_bfloat16*)carve((size_t)MROWS*DMODEL*2);
  __hip_bfloat16* mid_bf = (__hip_bfloat16*)carve((size_t)MROWS*4096*2);
  __hip_bfloat16* wqkv_t = (__hip_bfloat16*)carve((size_t)1536*1024*2);
  __hip_bfloat16* wo_t   = (__hip_bfloat16*)carve((size_t)1024*1024*2);
  __hip_bfloat16* w1_t   = (__hip_bfloat16*)carve((size_t)4096*1024*2);
  __hip_bfloat16* w2_t   = (__hip_bfloat16*)carve((size_t)1024*4096*2);
  // shared scratch: qkv split-2 partials (25.2 MB) early, then wo/w2 split-2
  // partials (16.8 MB). Lifetimes disjoint (qkv_p dead after rope2/vcast).
  char* scratch = carve((size_t)2*MROWS*1536*2);
  __hip_bfloat16* qkv_p = (__hip_bfloat16*)scratch;   // 2*MROWS*1536*2
  __hip_bfloat16* ps    = (__hip_bfloat16*)scratch;   // 2*MROWS*1024*2 fits
  _Float16* q_f  = (_Float16*)carve((size_t)BATCH*NH *S_LEN*64*2);
  _Float16* k_f  = (_Float16*)carve((size_t)BATCH*NKV*S_LEN*64*2);
  _Float16* vt_f = (_Float16*)carve((size_t)BATCH*NKV*64*S_LEN*2);
  float* x1   = (float*)carve((size_t)MROWS*DMODEL*4);
  float* ctab = (float*)carve((size_t)S_LEN*32*4);
  float* stab = (float*)carve((size_t)S_LEN*32*4);

  // weight prep + rmsnorm1 + rope table in one launch
  prep_k<<<10752 + MROWS + 256, 256, 0, stream>>>(wq, wk, wv, wo, w1, w2,
                                                  wqkv_t, wo_t, w1_t, w2_t, x, n1w, h_bf,
                                                  ctab, stab);

  // QKV: M=4096 N=1536 K=1024, split-K=2 (768 blocks), dbuf + 2D swizzle
  mgemm_k<3,true><<<dim3(12, 32, 2), 256, 0, stream>>>(h_bf, wqkv_t, nullptr, qkv_p, 1536, 1024, 512, 8);

  rope2_k<<<dim3(S_LEN, BATCH*20/4), 256, 0, stream>>>((const unsigned short*)qkv_p, bq, bk, qnw, knw, ctab, stab, q_f, k_f);
  vcast_k<<<dim3(S_LEN/64, BATCH*NKV), 256, 0, stream>>>((const unsigned short*)qkv_p, bv, vt_f);
  attn2_k<<<dim3(BATCH*NH, S_LEN/64), 256, 0, stream>>>(q_f, k_f, vt_f, ao_bf);

  // O-proj: M=4096 N=1024 K=1024, split-K=2 (512 blocks), dbuf + 2D swizzle
  mgemm_k<3,true><<<dim3(8, 32, 2), 256, 0, stream>>>(ao_bf, wo_t, nullptr, ps, 1024, 1024, 512, 8);
  // fused: reduce(+bias+res) -> x1 AND rmsnorm2 -> h_bf
  redn_k<2><<<MROWS, 256, 0, stream>>>((const unsigned short*)ps, bo, x, n2w, x1, h_bf);

  // MLP up: M=4096 N=4096 K=1024 (1024 blocks), dbuf + 2D swizzle, gelu fused
  mgemm_k<1,true><<<dim3(32, 32, 1), 256, 0, stream>>>(h_bf, w1_t, b1, mid_bf, 4096, 1024, 1024, 8);

  // MLP down: M=4096 N=1024 K=4096, split-K=2 (512 blocks), single-buf + 2D swizzle
  mgemm_k<3,false><<<dim3(8, 32, 2), 256, 0, stream>>>(mid_bf, w2_t, nullptr, ps, 1024, 4096, 2048, 4);
  reduce_k<2><<<4096, 256, 0, stream>>>((const unsigned short*)ps, b2, x1, out, 1024);
}